// Round 4
// baseline (723.231 us; speedup 1.0000x reference)
//
#include <hip/hip_runtime.h>

// PTDNet-GCN eval forward.
//  - L=2 hard-concrete samples identical in eval -> compute once.
//  - Edge MLP factors into per-node scalars s1/s2.
//  - CSR built via 2-phase counting sort (write-combined), not random scatter:
//    phase A bins edges into 32 row-range buckets (LDS FIFO -> coalesced bursts),
//    phase B builds row_start + csr_col per bucket with LDS hist/scan/cursors so
//    random writes stay inside one XCD's L2 (kills the 17x HBM write amplification).
//  - mask never materialized: k_dis computes dis; k_agg recomputes mask inline.
//  - H stored bf16x2 pre-scaled by dis[c] in the gemm epilogue.
// NOTE: packing assumes N < 2^17 (here N=100000) and rows-per-part < 2^12.

#define NPART 32
#define PCAP  53248   // per-bucket global capacity (mean 50000, sigma ~220)
#define CAPL  256     // per-bucket LDS fifo slots in phase A
#define RPP_MAX 3200  // max rows per partition in phase B LDS

__device__ inline float bf_lo(uint32_t u) { return __uint_as_float(u << 16); }
__device__ inline float bf_hi(uint32_t u) { return __uint_as_float(u & 0xffff0000u); }
__device__ inline uint32_t pack_bf2(float x, float y) {  // RTNE
  uint32_t bx = __float_as_uint(x), by = __float_as_uint(y);
  uint32_t rx = (bx + 0x7fffu + ((bx >> 16) & 1u)) >> 16;
  uint32_t ry = (by + 0x7fffu + ((by >> 16) & 1u)) >> 16;
  return (rx & 0xffffu) | (ry << 16);
}
__device__ inline float maskfn(float logit) {
  float g = 1.f / (1.f + __expf(-logit));
  return fminf(fmaxf(fmaf(g, 1.2f, -0.1f), 0.f), 1.f);  // ZETA-GAMMA=1.2, GAMMA=-0.1
}

// ---- Phase A: bin edges into NPART row-range buckets, write-combined ----
__global__ __launch_bounds__(256) void k_partA(const int* __restrict__ row,
                                               const int* __restrict__ col,
                                               int rpp, int E,
                                               uint32_t* __restrict__ part,
                                               int* __restrict__ gcur) {
  __shared__ uint32_t fifo[NPART][CAPL];
  __shared__ int fcnt[NPART];
  __shared__ int gbs;
  int tid = threadIdx.x;
  if (tid < NPART) fcnt[tid] = 0;
  __syncthreads();
  int chunk = (E + gridDim.x - 1) / gridDim.x;
  int s0 = blockIdx.x * chunk;
  int s1e = min(E, s0 + chunk);
  for (int base = s0; base < s1e; base += 256) {
    int e = base + tid;
    if (e < s1e) {
      int r = row[e], c = col[e];
      int b = r / rpp;
      uint32_t u = ((uint32_t)(r - b * rpp) << 17) | (uint32_t)c;
      int idx = atomicAdd(&fcnt[b], 1);
      if (idx < CAPL) fifo[b][idx] = u;
      else {  // statistically ~never (16 sigma); keep correct anyway
        int gp = atomicAdd(&gcur[b], 1);
        part[(size_t)b * PCAP + gp] = u;
      }
    }
  }
  __syncthreads();
  for (int b = 0; b < NPART; ++b) {
    int n = min(fcnt[b], CAPL);
    if (n == 0) continue;
    if (tid == 0) gbs = atomicAdd(&gcur[b], n);
    __syncthreads();
    for (int i = tid; i < n; i += 256) part[(size_t)b * PCAP + gbs + i] = fifo[b][i];
    __syncthreads();
  }
}

// ---- Phase B: per bucket, LDS hist -> scan -> row_start + csr_col ----
__global__ __launch_bounds__(1024) void k_partB(const uint32_t* __restrict__ part,
                                                const int* __restrict__ gcur,
                                                int rpp, int N,
                                                int* __restrict__ row_start,
                                                int* __restrict__ csr_col) {
  __shared__ int cnt[RPP_MAX];
  __shared__ int wsum[16];
  __shared__ int sh_base;
  int tid = threadIdx.x, lane = tid & 63, wid = tid >> 6;
  int p = blockIdx.x;
  if (tid == 0) {
    int b = 0;
    for (int q = 0; q < p; ++q) b += gcur[q];
    sh_base = b;
  }
  for (int j = tid; j < rpp; j += 1024) cnt[j] = 0;
  __syncthreads();
  int nb = gcur[p];
  int base = sh_base;
  const uint32_t* my = part + (size_t)p * PCAP;
  for (int i = tid; i < nb; i += 1024) atomicAdd(&cnt[my[i] >> 17], 1);
  __syncthreads();
  // exclusive scan of cnt[0..rpp): 4 rows/thread + wave scan + wave-partial scan
  int j0 = tid * 4;
  int v0 = (j0 + 0 < rpp) ? cnt[j0 + 0] : 0;
  int v1 = (j0 + 1 < rpp) ? cnt[j0 + 1] : 0;
  int v2 = (j0 + 2 < rpp) ? cnt[j0 + 2] : 0;
  int v3 = (j0 + 3 < rpp) ? cnt[j0 + 3] : 0;
  int s = v0 + v1 + v2 + v3;
  int incl = s;
#pragma unroll
  for (int off = 1; off < 64; off <<= 1) {
    int t = __shfl_up(incl, off);
    if (lane >= off) incl += t;
  }
  if (lane == 63) wsum[wid] = incl;
  __syncthreads();
  int wpre = 0;
  for (int w = 0; w < wid; ++w) wpre += wsum[w];
  int run = wpre + incl - s;  // exclusive prefix for this thread's 4 rows
  if (j0 + 0 < rpp) { cnt[j0 + 0] = run; run += v0; }
  if (j0 + 1 < rpp) { cnt[j0 + 1] = run; run += v1; }
  if (j0 + 2 < rpp) { cnt[j0 + 2] = run; run += v2; }
  if (j0 + 3 < rpp) { cnt[j0 + 3] = run; run += v3; }
  __syncthreads();
  for (int j = tid; j < rpp; j += 1024) {
    int gr = p * rpp + j;
    if (gr < N) row_start[gr] = base + cnt[j];
  }
  if (p == NPART - 1 && tid == 0) row_start[N] = base + nb;
  __syncthreads();  // row_start reads of cnt done before cursors mutate
  for (int i = tid; i < nb; i += 1024) {
    uint32_t u = my[i];
    int rl = u >> 17;
    int c = u & 0x1FFFF;
    int pos = base + atomicAdd(&cnt[rl], 1);
    csr_col[pos] = c;
  }
}

// ---- Per-node attention scalars ----
__global__ __launch_bounds__(256) void k_proj(const float* __restrict__ X,
                                              const float* __restrict__ W1,
                                              const float* __restrict__ b1,
                                              const float* __restrict__ W2,
                                              const float* __restrict__ b2,
                                              const float* __restrict__ aw,
                                              const float* __restrict__ attb,
                                              float* __restrict__ s1,
                                              float* __restrict__ s2, int N) {
  int n = blockIdx.x * 256 + threadIdx.x;
  if (n >= N) return;
  float a1[16], a2[16];
#pragma unroll
  for (int h = 0; h < 16; h++) { a1[h] = b1[h]; a2[h] = b2[h]; }
  const float4* xr = (const float4*)(X + (size_t)n * 128);
  for (int d4 = 0; d4 < 32; ++d4) {
    float4 xv = xr[d4];
#pragma unroll
    for (int q = 0; q < 4; q++) {
      float xs = ((const float*)&xv)[q];
      int d = d4 * 4 + q;
      const float4* w1r = (const float4*)(W1 + d * 16);
      const float4* w2r = (const float4*)(W2 + d * 16);
#pragma unroll
      for (int g = 0; g < 4; ++g) {
        float4 wa = w1r[g], wb = w2r[g];
        a1[g * 4 + 0] += xs * wa.x; a1[g * 4 + 1] += xs * wa.y;
        a1[g * 4 + 2] += xs * wa.z; a1[g * 4 + 3] += xs * wa.w;
        a2[g * 4 + 0] += xs * wb.x; a2[g * 4 + 1] += xs * wb.y;
        a2[g * 4 + 2] += xs * wb.z; a2[g * 4 + 3] += xs * wb.w;
      }
    }
  }
  float r1 = 0.f, r2 = 0.f;
#pragma unroll
  for (int h = 0; h < 16; h++) {
    r1 += fmaxf(a1[h], 0.f) * aw[h];
    r2 += fmaxf(a2[h], 0.f) * aw[16 + h];
  }
  s1[n] = r1;
  s2[n] = r2 + attb[0];
}

// ---- One wave per row: masked degree -> dis (masks recomputed later in agg) ----
__global__ __launch_bounds__(256) void k_dis(const int* __restrict__ rs,
                                             const int* __restrict__ csr_col,
                                             const float* __restrict__ s1,
                                             const float* __restrict__ s2,
                                             float* __restrict__ dis, int N) {
  int lane = threadIdx.x & 63, wid = threadIdx.x >> 6;
  int r = blockIdx.x * 4 + wid;
  if (r >= N) return;
  int start = rs[r], end = rs[r + 1];
  float s1r = s1[r];
  float sum = 0.f;
  for (int p = start + lane; p < end; p += 64) sum += maskfn(s1r + s2[csr_col[p]]);
#pragma unroll
  for (int off = 32; off > 0; off >>= 1) sum += __shfl_down(sum, off);
  if (lane == 0) dis[r] = rsqrtf(sum + 1.0f);
}

// ---- Hs = bf16x2( dis[n] * (X @ W)[n,:] ) ----
template <int DOUT>
__global__ __launch_bounds__(256) void k_gemm(const float* __restrict__ X,
                                              const float* __restrict__ W,
                                              const float* __restrict__ dis,
                                              uint32_t* __restrict__ Hs, int N) {
  constexpr int CPT = DOUT / 4;
  __shared__ float Ws[64 * DOUT];
  __shared__ float Xs[64][68];
  int tid = threadIdx.x;
  int n0 = blockIdx.x * 64;
  int nl = tid >> 2, cq = tid & 3;
  int nvalid = min(64, N - n0);
  float acc[CPT];
#pragma unroll
  for (int j = 0; j < CPT; j++) acc[j] = 0.f;
  for (int dt = 0; dt < 2; ++dt) {
    __syncthreads();
    const float4* Wg = (const float4*)(W + dt * 64 * DOUT);
    float4* Ws4 = (float4*)Ws;
    for (int i = tid; i < 64 * DOUT / 4; i += 256) Ws4[i] = Wg[i];
    for (int i = tid; i < nvalid * 16; i += 256) {
      int rl = i >> 4, d4 = i & 15;
      float4 v = *(const float4*)(X + (size_t)(n0 + rl) * 128 + dt * 64 + d4 * 4);
      Xs[rl][d4 * 4 + 0] = v.x; Xs[rl][d4 * 4 + 1] = v.y;
      Xs[rl][d4 * 4 + 2] = v.z; Xs[rl][d4 * 4 + 3] = v.w;
    }
    __syncthreads();
#pragma unroll 8
    for (int d = 0; d < 64; ++d) {
      float xv = Xs[nl][d];
#pragma unroll
      for (int jj = 0; jj < CPT / 4; ++jj) {
        const float4 w = *(const float4*)&Ws[d * DOUT + (cq + jj * 4) * 4];
        acc[jj * 4 + 0] = fmaf(xv, w.x, acc[jj * 4 + 0]);
        acc[jj * 4 + 1] = fmaf(xv, w.y, acc[jj * 4 + 1]);
        acc[jj * 4 + 2] = fmaf(xv, w.z, acc[jj * 4 + 2]);
        acc[jj * 4 + 3] = fmaf(xv, w.w, acc[jj * 4 + 3]);
      }
    }
  }
  int n = n0 + nl;
  if (n < N) {
    float d = dis[n];
    uint32_t* Hr = Hs + (size_t)n * (DOUT / 2);
#pragma unroll
    for (int jj = 0; jj < CPT / 4; jj++) {
      uint2 o;
      o.x = pack_bf2(d * acc[jj * 4 + 0], d * acc[jj * 4 + 1]);
      o.y = pack_bf2(d * acc[jj * 4 + 2], d * acc[jj * 4 + 3]);
      *(uint2*)&Hr[(cq + jj * 4) * 2] = o;
    }
  }
}

// ---- One wave per row, mask recomputed inline from s1/s2 ----
//   LPE = DOUT/4 lanes per edge (uint2 = 4 bf16 feats), EPI = 64/LPE edges/iter.
// out[r] = act( dis[r] * ( sum_e mask_e * Hs[col_e] + Hs[r] ) ).
template <int DOUT, bool RELU>
__global__ __launch_bounds__(256) void k_agg(const int* __restrict__ rs,
                                             const int* __restrict__ csr_col,
                                             const float* __restrict__ s1,
                                             const float* __restrict__ s2,
                                             const float* __restrict__ dis,
                                             const uint32_t* __restrict__ Hs,
                                             float* __restrict__ out, int N) {
  constexpr int LPE = DOUT / 4;
  constexpr int EPI = 64 / LPE;
  int lane = threadIdx.x & 63, wid = threadIdx.x >> 6;
  int r = blockIdx.x * 4 + wid;
  if (r >= N) return;
  int start = rs[r], end = rs[r + 1];
  float s1r = s1[r];
  int sub = lane / LPE;
  int fl = lane & (LPE - 1);
  float a0 = 0.f, a1 = 0.f, a2 = 0.f, a3 = 0.f;
  {  // self term (mask == 1), only in group 0
    uint2 u = *(const uint2*)(Hs + (size_t)r * (DOUT / 2) + fl * 2);
    if (sub == 0) { a0 = bf_lo(u.x); a1 = bf_hi(u.x); a2 = bf_lo(u.y); a3 = bf_hi(u.y); }
  }
  int p = start;
  for (; p + 2 * EPI <= end; p += 2 * EPI) {
    int eA = p + sub, eB = p + EPI + sub;
    int cA = csr_col[eA], cB = csr_col[eB];
    float mA = maskfn(s1r + s2[cA]);
    float mB = maskfn(s1r + s2[cB]);
    uint2 uA = *(const uint2*)(Hs + (size_t)cA * (DOUT / 2) + fl * 2);
    uint2 uB = *(const uint2*)(Hs + (size_t)cB * (DOUT / 2) + fl * 2);
    a0 = fmaf(mA, bf_lo(uA.x), a0); a1 = fmaf(mA, bf_hi(uA.x), a1);
    a2 = fmaf(mA, bf_lo(uA.y), a2); a3 = fmaf(mA, bf_hi(uA.y), a3);
    a0 = fmaf(mB, bf_lo(uB.x), a0); a1 = fmaf(mB, bf_hi(uB.x), a1);
    a2 = fmaf(mB, bf_lo(uB.y), a2); a3 = fmaf(mB, bf_hi(uB.y), a3);
  }
  for (; p < end; p += EPI) {
    int e = p + sub;
    bool v = e < end;
    int c = v ? csr_col[e] : r;
    float m = v ? maskfn(s1r + s2[c]) : 0.f;
    uint2 u = *(const uint2*)(Hs + (size_t)c * (DOUT / 2) + fl * 2);
    a0 = fmaf(m, bf_lo(u.x), a0); a1 = fmaf(m, bf_hi(u.x), a1);
    a2 = fmaf(m, bf_lo(u.y), a2); a3 = fmaf(m, bf_hi(u.y), a3);
  }
#pragma unroll
  for (int off = LPE; off < 64; off <<= 1) {
    a0 += __shfl_xor(a0, off); a1 += __shfl_xor(a1, off);
    a2 += __shfl_xor(a2, off); a3 += __shfl_xor(a3, off);
  }
  if (lane < LPE) {
    float dr = dis[r];
    float4 o = make_float4(dr * a0, dr * a1, dr * a2, dr * a3);
    if (RELU) {
      o.x = fmaxf(o.x, 0.f); o.y = fmaxf(o.y, 0.f);
      o.z = fmaxf(o.z, 0.f); o.w = fmaxf(o.w, 0.f);
    }
    *(float4*)(out + (size_t)r * DOUT + fl * 4) = o;
  }
}

extern "C" void kernel_launch(void* const* d_in, const int* in_sizes, int n_in,
                              void* d_out, int out_size, void* d_ws, size_t ws_size,
                              hipStream_t stream) {
  const float* x      = (const float*)d_in[0];
  const int*   row    = (const int*)d_in[1];
  const int*   col    = (const int*)d_in[2];
  const float* nb_w   = (const float*)d_in[3];
  const float* nb_b   = (const float*)d_in[4];
  const float* self_w = (const float*)d_in[5];
  const float* self_b = (const float*)d_in[6];
  const float* att_w  = (const float*)d_in[7];
  const float* att_b  = (const float*)d_in[8];
  const float* w0     = (const float*)d_in[9];
  const float* w1     = (const float*)d_in[10];
  float* out = (float*)d_out;

  const int N = in_sizes[0] / 128;
  const int E = in_sizes[1];
  const int rpp = (N + NPART - 1) / NPART;  // 3125 for N=100000 (< RPP_MAX)

  char* wp = (char*)d_ws;
  auto alloc = [&](size_t bytes) -> void* {
    void* q = (void*)wp;
    wp += (bytes + 255) & ~(size_t)255;
    return q;
  };
  int*      row_start = (int*)alloc((size_t)(N + 1) * 4);
  int*      gcur      = (int*)alloc(NPART * 4);
  int*      csr_col   = (int*)alloc((size_t)E * 4);
  float*    s1        = (float*)alloc((size_t)N * 4);
  float*    s2        = (float*)alloc((size_t)N * 4);
  float*    dis       = (float*)alloc((size_t)N * 4);
  uint32_t* hs        = (uint32_t*)alloc((size_t)N * 64 * 4);  // bf16x2 H; ALSO phase-A/B
                                                               // part list (6.8MB, dead
                                                               // before gemm writes hs)
  float*    X1        = (float*)alloc((size_t)N * 128 * 4);
  uint32_t* part      = hs;

  const int gw = (N + 3) / 4;
  const int gp = (N + 255) / 256;
  const int gg = (N + 63) / 64;

  // ---- CSR build: 2-phase counting sort ----
  hipMemsetAsync(gcur, 0, NPART * 4, stream);
  k_partA<<<512, 256, 0, stream>>>(row, col, rpp, E, part, gcur);
  k_partB<<<NPART, 1024, 0, stream>>>(part, gcur, rpp, N, row_start, csr_col);

  // ---- layer 0: din=128, dout=128, relu ----
  k_proj<<<gp, 256, 0, stream>>>(x, nb_w, nb_b, self_w, self_b, att_w, att_b, s1, s2, N);
  k_dis<<<gw, 256, 0, stream>>>(row_start, csr_col, s1, s2, dis, N);
  k_gemm<128><<<gg, 256, 0, stream>>>(x, w0, dis, hs, N);
  k_agg<128, true><<<gw, 256, 0, stream>>>(row_start, csr_col, s1, s2, dis, hs, X1, N);

  // ---- layer 1: din=128, dout=64, identity ----
  k_proj<<<gp, 256, 0, stream>>>(X1, nb_w + 2048, nb_b + 16, self_w + 2048, self_b + 16,
                                 att_w + 32, att_b + 1, s1, s2, N);
  k_dis<<<gw, 256, 0, stream>>>(row_start, csr_col, s1, s2, dis, N);
  k_gemm<64><<<gg, 256, 0, stream>>>(X1, w1, dis, hs, N);
  k_agg<64, false><<<gw, 256, 0, stream>>>(row_start, csr_col, s1, s2, dis, hs, out, N);
}

// Round 5
// 632.113 us; speedup vs baseline: 1.1441x; 1.1441x over previous
//
#include <hip/hip_runtime.h>

// PTDNet-GCN eval forward.
//  - L=2 hard-concrete samples identical in eval -> compute once.
//  - Edge MLP factors into per-node scalars s1/s2.
//  - CSR build: hist + scan + scatter, with hist/scatter partitioned into 8
//    row-range groups keyed by blockIdx%8 (~XCD id under round-robin dispatch).
//    Each group's atomics/writes stay in one XCD's L2 (50KB cursors, 800KB csr
//    slice) -> full-line writebacks, no cross-XCD line bouncing. The 8x
//    redundant edge reads (12.8MB total) are L3-resident => ~free.
//  - mask never materialized: k_dis computes dis; k_agg recomputes mask inline.
//  - H stored bf16x2 pre-scaled by dis[c] in the gemm epilogue.

__device__ inline float bf_lo(uint32_t u) { return __uint_as_float(u << 16); }
__device__ inline float bf_hi(uint32_t u) { return __uint_as_float(u & 0xffff0000u); }
__device__ inline uint32_t pack_bf2(float x, float y) {  // RTNE
  uint32_t bx = __float_as_uint(x), by = __float_as_uint(y);
  uint32_t rx = (bx + 0x7fffu + ((bx >> 16) & 1u)) >> 16;
  uint32_t ry = (by + 0x7fffu + ((by >> 16) & 1u)) >> 16;
  return (rx & 0xffffu) | (ry << 16);
}
__device__ inline float maskfn(float logit) {
  float g = 1.f / (1.f + __expf(-logit));
  return fminf(fmaxf(fmaf(g, 1.2f, -0.1f), 0.f), 1.f);  // ZETA-GAMMA=1.2, GAMMA=-0.1
}

// ---- histogram, row-range partitioned by blockIdx%8 ----
__global__ __launch_bounds__(256) void k_hist8(const int* __restrict__ row,
                                               int* __restrict__ counts, int E, int N) {
  int g = blockIdx.x & 7;
  int bj = blockIdx.x >> 3, nbj = gridDim.x >> 3;
  int lo = (int)(((long long)N * g) >> 3);
  int hi = (int)(((long long)N * (g + 1)) >> 3);
  for (int e = bj * 256 + threadIdx.x; e < E; e += nbj * 256) {
    int r = row[e];
    if (r >= lo && r < hi) atomicAdd(&counts[r], 1);
  }
}

__global__ __launch_bounds__(256) void k_blocksum(const int* __restrict__ counts,
                                                  int* __restrict__ bsum, int N) {
  __shared__ int sdata[256];
  int base = blockIdx.x * 1024;
  int s = 0;
#pragma unroll
  for (int k = 0; k < 4; k++) {
    int i = base + k * 256 + threadIdx.x;
    if (i < N) s += counts[i];
  }
  sdata[threadIdx.x] = s;
  __syncthreads();
  for (int off = 128; off > 0; off >>= 1) {
    if (threadIdx.x < off) sdata[threadIdx.x] += sdata[threadIdx.x + off];
    __syncthreads();
  }
  if (threadIdx.x == 0) bsum[blockIdx.x] = sdata[0];
}

__global__ __launch_bounds__(128) void k_scanpart(const int* __restrict__ bsum,
                                                  int* __restrict__ boff, int NB,
                                                  int* __restrict__ row_start, int N) {
  __shared__ int s[129];
  int t = threadIdx.x;
  s[t] = (t < NB) ? bsum[t] : 0;
  __syncthreads();
  if (t == 0) {
    int r = 0;
    for (int b = 0; b < NB; b++) { int v = s[b]; s[b] = r; r += v; }
    row_start[N] = r;  // == E
  }
  __syncthreads();
  if (t < NB) boff[t] = s[t];
}

__global__ __launch_bounds__(256) void k_scanblk(const int* __restrict__ counts,
                                                 const int* __restrict__ boff,
                                                 int* __restrict__ row_start, int N) {
  __shared__ int warp_sums[4];
  int tid = threadIdx.x, lane = tid & 63, wid = tid >> 6;
  int base = blockIdx.x * 1024;
  int i0 = base + tid * 4;
  int c0, c1, c2, c3;
  if (i0 + 3 < N) {
    int4 v = *(const int4*)(counts + i0);
    c0 = v.x; c1 = v.y; c2 = v.z; c3 = v.w;
  } else {
    c0 = (i0 + 0 < N) ? counts[i0 + 0] : 0;
    c1 = (i0 + 1 < N) ? counts[i0 + 1] : 0;
    c2 = (i0 + 2 < N) ? counts[i0 + 2] : 0;
    c3 = (i0 + 3 < N) ? counts[i0 + 3] : 0;
  }
  int s = c0 + c1 + c2 + c3;
  int incl = s;
#pragma unroll
  for (int off = 1; off < 64; off <<= 1) {
    int v = __shfl_up(incl, off);
    if (lane >= off) incl += v;
  }
  if (lane == 63) warp_sums[wid] = incl;
  __syncthreads();
  int pre = 0;
  for (int w = 0; w < wid; w++) pre += warp_sums[w];
  int run = boff[blockIdx.x] + pre + incl - s;
  if (i0 + 0 < N) row_start[i0 + 0] = run; run += c0;
  if (i0 + 1 < N) row_start[i0 + 1] = run; run += c1;
  if (i0 + 2 < N) row_start[i0 + 2] = run; run += c2;
  if (i0 + 3 < N) row_start[i0 + 3] = run;
}

// ---- scatter, row-range partitioned; atomicSub(counts) avoids cursor memset ----
__global__ __launch_bounds__(256) void k_scatter8(const int* __restrict__ row,
                                                  const int* __restrict__ col,
                                                  const int* __restrict__ row_start,
                                                  int* __restrict__ counts,
                                                  int* __restrict__ csr_col, int E, int N) {
  int g = blockIdx.x & 7;
  int bj = blockIdx.x >> 3, nbj = gridDim.x >> 3;
  int lo = (int)(((long long)N * g) >> 3);
  int hi = (int)(((long long)N * (g + 1)) >> 3);
  for (int e = bj * 256 + threadIdx.x; e < E; e += nbj * 256) {
    int r = row[e];
    if (r >= lo && r < hi) {
      int c = col[e];
      int old = atomicSub(&counts[r], 1);  // deg -> 0; fills row backward
      csr_col[row_start[r] + old - 1] = c;
    }
  }
}

// ---- Per-node attention scalars ----
__global__ __launch_bounds__(256) void k_proj(const float* __restrict__ X,
                                              const float* __restrict__ W1,
                                              const float* __restrict__ b1,
                                              const float* __restrict__ W2,
                                              const float* __restrict__ b2,
                                              const float* __restrict__ aw,
                                              const float* __restrict__ attb,
                                              float* __restrict__ s1,
                                              float* __restrict__ s2, int N) {
  int n = blockIdx.x * 256 + threadIdx.x;
  if (n >= N) return;
  float a1[16], a2[16];
#pragma unroll
  for (int h = 0; h < 16; h++) { a1[h] = b1[h]; a2[h] = b2[h]; }
  const float4* xr = (const float4*)(X + (size_t)n * 128);
  for (int d4 = 0; d4 < 32; ++d4) {
    float4 xv = xr[d4];
#pragma unroll
    for (int q = 0; q < 4; q++) {
      float xs = ((const float*)&xv)[q];
      int d = d4 * 4 + q;
      const float4* w1r = (const float4*)(W1 + d * 16);
      const float4* w2r = (const float4*)(W2 + d * 16);
#pragma unroll
      for (int g = 0; g < 4; ++g) {
        float4 wa = w1r[g], wb = w2r[g];
        a1[g * 4 + 0] += xs * wa.x; a1[g * 4 + 1] += xs * wa.y;
        a1[g * 4 + 2] += xs * wa.z; a1[g * 4 + 3] += xs * wa.w;
        a2[g * 4 + 0] += xs * wb.x; a2[g * 4 + 1] += xs * wb.y;
        a2[g * 4 + 2] += xs * wb.z; a2[g * 4 + 3] += xs * wb.w;
      }
    }
  }
  float r1 = 0.f, r2 = 0.f;
#pragma unroll
  for (int h = 0; h < 16; h++) {
    r1 += fmaxf(a1[h], 0.f) * aw[h];
    r2 += fmaxf(a2[h], 0.f) * aw[16 + h];
  }
  s1[n] = r1;
  s2[n] = r2 + attb[0];
}

// ---- One wave per row: masked degree -> dis ----
__global__ __launch_bounds__(256) void k_dis(const int* __restrict__ rs,
                                             const int* __restrict__ csr_col,
                                             const float* __restrict__ s1,
                                             const float* __restrict__ s2,
                                             float* __restrict__ dis, int N) {
  int lane = threadIdx.x & 63, wid = threadIdx.x >> 6;
  int r = blockIdx.x * 4 + wid;
  if (r >= N) return;
  int start = rs[r], end = rs[r + 1];
  float s1r = s1[r];
  float sum = 0.f;
  for (int p = start + lane; p < end; p += 64) sum += maskfn(s1r + s2[csr_col[p]]);
#pragma unroll
  for (int off = 32; off > 0; off >>= 1) sum += __shfl_down(sum, off);
  if (lane == 0) dis[r] = rsqrtf(sum + 1.0f);
}

// ---- Hs = bf16x2( dis[n] * (X @ W)[n,:] ) ----
template <int DOUT>
__global__ __launch_bounds__(256) void k_gemm(const float* __restrict__ X,
                                              const float* __restrict__ W,
                                              const float* __restrict__ dis,
                                              uint32_t* __restrict__ Hs, int N) {
  constexpr int CPT = DOUT / 4;
  __shared__ float Ws[64 * DOUT];
  __shared__ float Xs[64][68];
  int tid = threadIdx.x;
  int n0 = blockIdx.x * 64;
  int nl = tid >> 2, cq = tid & 3;
  int nvalid = min(64, N - n0);
  float acc[CPT];
#pragma unroll
  for (int j = 0; j < CPT; j++) acc[j] = 0.f;
  for (int dt = 0; dt < 2; ++dt) {
    __syncthreads();
    const float4* Wg = (const float4*)(W + dt * 64 * DOUT);
    float4* Ws4 = (float4*)Ws;
    for (int i = tid; i < 64 * DOUT / 4; i += 256) Ws4[i] = Wg[i];
    for (int i = tid; i < nvalid * 16; i += 256) {
      int rl = i >> 4, d4 = i & 15;
      float4 v = *(const float4*)(X + (size_t)(n0 + rl) * 128 + dt * 64 + d4 * 4);
      Xs[rl][d4 * 4 + 0] = v.x; Xs[rl][d4 * 4 + 1] = v.y;
      Xs[rl][d4 * 4 + 2] = v.z; Xs[rl][d4 * 4 + 3] = v.w;
    }
    __syncthreads();
#pragma unroll 8
    for (int d = 0; d < 64; ++d) {
      float xv = Xs[nl][d];
#pragma unroll
      for (int jj = 0; jj < CPT / 4; ++jj) {
        const float4 w = *(const float4*)&Ws[d * DOUT + (cq + jj * 4) * 4];
        acc[jj * 4 + 0] = fmaf(xv, w.x, acc[jj * 4 + 0]);
        acc[jj * 4 + 1] = fmaf(xv, w.y, acc[jj * 4 + 1]);
        acc[jj * 4 + 2] = fmaf(xv, w.z, acc[jj * 4 + 2]);
        acc[jj * 4 + 3] = fmaf(xv, w.w, acc[jj * 4 + 3]);
      }
    }
  }
  int n = n0 + nl;
  if (n < N) {
    float d = dis[n];
    uint32_t* Hr = Hs + (size_t)n * (DOUT / 2);
#pragma unroll
    for (int jj = 0; jj < CPT / 4; jj++) {
      uint2 o;
      o.x = pack_bf2(d * acc[jj * 4 + 0], d * acc[jj * 4 + 1]);
      o.y = pack_bf2(d * acc[jj * 4 + 2], d * acc[jj * 4 + 3]);
      *(uint2*)&Hr[(cq + jj * 4) * 2] = o;
    }
  }
}

// ---- One wave per row, mask recomputed inline from s1/s2 ----
template <int DOUT, bool RELU>
__global__ __launch_bounds__(256) void k_agg(const int* __restrict__ rs,
                                             const int* __restrict__ csr_col,
                                             const float* __restrict__ s1,
                                             const float* __restrict__ s2,
                                             const float* __restrict__ dis,
                                             const uint32_t* __restrict__ Hs,
                                             float* __restrict__ out, int N) {
  constexpr int LPE = DOUT / 4;
  constexpr int EPI = 64 / LPE;
  int lane = threadIdx.x & 63, wid = threadIdx.x >> 6;
  int r = blockIdx.x * 4 + wid;
  if (r >= N) return;
  int start = rs[r], end = rs[r + 1];
  float s1r = s1[r];
  int sub = lane / LPE;
  int fl = lane & (LPE - 1);
  float a0 = 0.f, a1 = 0.f, a2 = 0.f, a3 = 0.f;
  {  // self term (mask == 1), only in group 0
    uint2 u = *(const uint2*)(Hs + (size_t)r * (DOUT / 2) + fl * 2);
    if (sub == 0) { a0 = bf_lo(u.x); a1 = bf_hi(u.x); a2 = bf_lo(u.y); a3 = bf_hi(u.y); }
  }
  int p = start;
  for (; p + 2 * EPI <= end; p += 2 * EPI) {
    int eA = p + sub, eB = p + EPI + sub;
    int cA = csr_col[eA], cB = csr_col[eB];
    float mA = maskfn(s1r + s2[cA]);
    float mB = maskfn(s1r + s2[cB]);
    uint2 uA = *(const uint2*)(Hs + (size_t)cA * (DOUT / 2) + fl * 2);
    uint2 uB = *(const uint2*)(Hs + (size_t)cB * (DOUT / 2) + fl * 2);
    a0 = fmaf(mA, bf_lo(uA.x), a0); a1 = fmaf(mA, bf_hi(uA.x), a1);
    a2 = fmaf(mA, bf_lo(uA.y), a2); a3 = fmaf(mA, bf_hi(uA.y), a3);
    a0 = fmaf(mB, bf_lo(uB.x), a0); a1 = fmaf(mB, bf_hi(uB.x), a1);
    a2 = fmaf(mB, bf_lo(uB.y), a2); a3 = fmaf(mB, bf_hi(uB.y), a3);
  }
  for (; p < end; p += EPI) {
    int e = p + sub;
    bool v = e < end;
    int c = v ? csr_col[e] : r;
    float m = v ? maskfn(s1r + s2[c]) : 0.f;
    uint2 u = *(const uint2*)(Hs + (size_t)c * (DOUT / 2) + fl * 2);
    a0 = fmaf(m, bf_lo(u.x), a0); a1 = fmaf(m, bf_hi(u.x), a1);
    a2 = fmaf(m, bf_lo(u.y), a2); a3 = fmaf(m, bf_hi(u.y), a3);
  }
#pragma unroll
  for (int off = LPE; off < 64; off <<= 1) {
    a0 += __shfl_xor(a0, off); a1 += __shfl_xor(a1, off);
    a2 += __shfl_xor(a2, off); a3 += __shfl_xor(a3, off);
  }
  if (lane < LPE) {
    float dr = dis[r];
    float4 o = make_float4(dr * a0, dr * a1, dr * a2, dr * a3);
    if (RELU) {
      o.x = fmaxf(o.x, 0.f); o.y = fmaxf(o.y, 0.f);
      o.z = fmaxf(o.z, 0.f); o.w = fmaxf(o.w, 0.f);
    }
    *(float4*)(out + (size_t)r * DOUT + fl * 4) = o;
  }
}

extern "C" void kernel_launch(void* const* d_in, const int* in_sizes, int n_in,
                              void* d_out, int out_size, void* d_ws, size_t ws_size,
                              hipStream_t stream) {
  const float* x      = (const float*)d_in[0];
  const int*   row    = (const int*)d_in[1];
  const int*   col    = (const int*)d_in[2];
  const float* nb_w   = (const float*)d_in[3];
  const float* nb_b   = (const float*)d_in[4];
  const float* self_w = (const float*)d_in[5];
  const float* self_b = (const float*)d_in[6];
  const float* att_w  = (const float*)d_in[7];
  const float* att_b  = (const float*)d_in[8];
  const float* w0     = (const float*)d_in[9];
  const float* w1     = (const float*)d_in[10];
  float* out = (float*)d_out;

  const int N = in_sizes[0] / 128;
  const int E = in_sizes[1];

  char* wp = (char*)d_ws;
  auto alloc = [&](size_t bytes) -> void* {
    void* q = (void*)wp;
    wp += (bytes + 255) & ~(size_t)255;
    return q;
  };
  int*      counts    = (int*)alloc((size_t)N * 4);   // degree, then scatter cursor
  int*      row_start = (int*)alloc((size_t)(N + 1) * 4);
  int*      bsum      = (int*)alloc(512);
  int*      boff      = (int*)alloc(512);
  int*      csr_col   = (int*)alloc((size_t)E * 4);
  float*    s1        = (float*)alloc((size_t)N * 4);
  float*    s2        = (float*)alloc((size_t)N * 4);
  float*    dis       = (float*)alloc((size_t)N * 4);
  uint32_t* hs        = (uint32_t*)alloc((size_t)N * 64 * 4);  // bf16x2, up to 128 feats
  float*    X1        = (float*)alloc((size_t)N * 128 * 4);

  const int NB = (N + 1023) / 1024;  // 98 (<=128)
  const int gw = (N + 3) / 4;
  const int gp = (N + 255) / 256;
  const int gg = (N + 63) / 64;

  // ---- CSR build: partitioned hist -> scan -> partitioned scatter ----
  hipMemsetAsync(counts, 0, (size_t)N * 4, stream);
  k_hist8<<<2048, 256, 0, stream>>>(row, counts, E, N);
  k_blocksum<<<NB, 256, 0, stream>>>(counts, bsum, N);
  k_scanpart<<<1, 128, 0, stream>>>(bsum, boff, NB, row_start, N);
  k_scanblk<<<NB, 256, 0, stream>>>(counts, boff, row_start, N);
  k_scatter8<<<2048, 256, 0, stream>>>(row, col, row_start, counts, csr_col, E, N);

  // ---- layer 0: din=128, dout=128, relu ----
  k_proj<<<gp, 256, 0, stream>>>(x, nb_w, nb_b, self_w, self_b, att_w, att_b, s1, s2, N);
  k_dis<<<gw, 256, 0, stream>>>(row_start, csr_col, s1, s2, dis, N);
  k_gemm<128><<<gg, 256, 0, stream>>>(x, w0, dis, hs, N);
  k_agg<128, true><<<gw, 256, 0, stream>>>(row_start, csr_col, s1, s2, dis, hs, X1, N);

  // ---- layer 1: din=128, dout=64, identity ----
  k_proj<<<gp, 256, 0, stream>>>(X1, nb_w + 2048, nb_b + 16, self_w + 2048, self_b + 16,
                                 att_w + 32, att_b + 1, s1, s2, N);
  k_dis<<<gw, 256, 0, stream>>>(row_start, csr_col, s1, s2, dis, N);
  k_gemm<64><<<gg, 256, 0, stream>>>(X1, w1, dis, hs, N);
  k_agg<64, false><<<gw, 256, 0, stream>>>(row_start, csr_col, s1, s2, dis, hs, out, N);
}

// Round 7
// 498.900 us; speedup vs baseline: 1.4497x; 1.2670x over previous
//
#include <hip/hip_runtime.h>

// PTDNet-GCN eval forward.
//  - L=2 hard-concrete samples identical in eval -> compute once.
//  - Edge MLP factors into per-node scalars s1/s2; its 128->16 matmuls and the
//    GCN 128->{128,64} matmuls all run as bf16 MFMA (16x16x32), A read straight
//    from global bf16 rows (no LDS), B pre-packed into per-lane fragments.
//  - CSR build: hist/scatter partitioned into 8 row-ranges by blockIdx%8 (~XCD)
//    so random atomics/writes stay in one XCD's L2 (fixes 17x write amplif.).
//  - mask never materialized: k_dis computes dis; k_agg recomputes mask inline.
//  - All inter-kernel feature tensors bf16 (xb, Ha, Hs, x1b); Hs pre-scaled by
//    dis[c] so agg's per-edge work is gather+fma only.
// FIX vs r5: k_wpack att branch used layer = rem>>11 (2048) instead of >>12
// (4096/layer) -> aW0 scrambled + OOB + aW1 never written. Rewritten cleanly.

typedef __attribute__((ext_vector_type(8))) short bf16x8;
typedef __attribute__((ext_vector_type(4))) float f32x4;

__device__ inline float bf_lo(uint32_t u) { return __uint_as_float(u << 16); }
__device__ inline float bf_hi(uint32_t u) { return __uint_as_float(u & 0xffff0000u); }
__device__ inline ushort bf1(float x) {  // RTNE
  uint32_t b = __float_as_uint(x);
  return (ushort)((b + 0x7fffu + ((b >> 16) & 1u)) >> 16);
}
__device__ inline uint32_t pack_bf2(float x, float y) {
  return (uint32_t)bf1(x) | ((uint32_t)bf1(y) << 16);
}
__device__ inline float maskfn(float logit) {
  float g = 1.f / (1.f + __expf(-logit));
  return fminf(fmaxf(fmaf(g, 1.2f, -0.1f), 0.f), 1.f);  // ZETA-GAMMA=1.2, GAMMA=-0.1
}

// ---- f32 -> bf16 row conversion (8 elems/thread) ----
__global__ __launch_bounds__(256) void k_cvt(const float* __restrict__ X,
                                             ushort* __restrict__ Xb, int n8) {
  int i = blockIdx.x * 256 + threadIdx.x;
  if (i >= n8) return;
  const float4* s = (const float4*)(X + (size_t)i * 8);
  float4 v0 = s[0], v1 = s[1];
  uint4 o;
  o.x = pack_bf2(v0.x, v0.y); o.y = pack_bf2(v0.z, v0.w);
  o.z = pack_bf2(v1.x, v1.y); o.w = pack_bf2(v1.z, v1.w);
  *(uint4*)(Xb + (size_t)i * 8) = o;
}

// ---- pack all weight matrices into MFMA B-fragment order ----
// Fragment index within a matrix: frag = ((ct*4+g)*64+l)*8+j  (ct|g|l|j bits),
// stores bf16( W[k][col] ) with k = g*32+(l>>4)*8+j, col = ct*16+(l&15).
// w0b: 16384 (ct<8), w1b: 8192 (ct<4), aW{0,1}: 4096 each (ct0=nb_w, ct1=self_w).
__global__ __launch_bounds__(256) void k_wpack(const float* __restrict__ w0,
                                               const float* __restrict__ w1,
                                               const float* __restrict__ nbw,
                                               const float* __restrict__ sfw,
                                               ushort* __restrict__ w0b,
                                               ushort* __restrict__ w1b,
                                               ushort* __restrict__ aW0,
                                               ushort* __restrict__ aW1) {
  int t = blockIdx.x * 256 + threadIdx.x;
  if (t < 16384) {
    int j = t & 7, l = (t >> 3) & 63, g = (t >> 9) & 3, ct = t >> 11;
    int k = g * 32 + (l >> 4) * 8 + j;
    w0b[t] = bf1(w0[k * 128 + ct * 16 + (l & 15)]);
  } else if (t < 24576) {
    int rem = t - 16384;
    int j = rem & 7, l = (rem >> 3) & 63, g = (rem >> 9) & 3, ct = rem >> 11;
    int k = g * 32 + (l >> 4) * 8 + j;
    w1b[rem] = bf1(w1[k * 64 + ct * 16 + (l & 15)]);
  } else if (t < 32768) {
    int rem = t - 24576;            // [0, 8192)
    int layer = rem >> 12;          // 4096 per layer
    int full = rem & 4095;          // ct(1b) | g(2b) | l(6b) | j(3b)
    int j = full & 7, l = (full >> 3) & 63, g = (full >> 9) & 3, ct = full >> 11;
    int k = g * 32 + (l >> 4) * 8 + j;
    const float* src = (ct == 0 ? nbw : sfw) + layer * 2048;  // [128][16] slab
    ushort* dst = (layer == 0 ? aW0 : aW1);
    dst[full] = bf1(src[k * 16 + (l & 15)]);
  }
}

// ---- MFMA GEMM: H[N,DOUT](bf16) = Xb[N,128] @ Wp, epilogue dis-scale or bias ----
template <int DOUT, bool SCALE_DIS>
__global__ __launch_bounds__(256) void k_mgemm(const ushort* __restrict__ Xb,
                                               const ushort* __restrict__ Wp,
                                               const float* __restrict__ dis,
                                               const float* __restrict__ b1,
                                               const float* __restrict__ b2,
                                               ushort* __restrict__ H, int N) {
  constexpr int NCT = DOUT / 16;
  int tid = threadIdx.x, w = tid >> 6, l = tid & 63;
  int n0 = blockIdx.x * 64 + w * 16;
  int arow = n0 + (l & 15);
  if (arow >= N) arow = N - 1;
  const ushort* xr = Xb + (size_t)arow * 128 + (l >> 4) * 8;
  bf16x8 a[4];
#pragma unroll
  for (int g = 0; g < 4; ++g) a[g] = *(const bf16x8*)(xr + g * 32);
  f32x4 acc[NCT];
#pragma unroll
  for (int ct = 0; ct < NCT; ++ct) acc[ct] = (f32x4){0.f, 0.f, 0.f, 0.f};
  const ushort* wp = Wp + l * 8;
#pragma unroll
  for (int ct = 0; ct < NCT; ++ct) {
#pragma unroll
    for (int g = 0; g < 4; ++g) {
      bf16x8 b = *(const bf16x8*)(wp + (size_t)(ct * 4 + g) * 512);
      acc[ct] = __builtin_amdgcn_mfma_f32_16x16x32_bf16(a[g], b, acc[ct], 0, 0, 0);
    }
  }
  int r0 = n0 + (l >> 4) * 4;  // C/D: col=lane&15, row=(lane>>4)*4+reg [m89]
  float scale[4];
#pragma unroll
  for (int r = 0; r < 4; ++r)
    scale[r] = SCALE_DIS ? ((r0 + r < N) ? dis[r0 + r] : 0.f) : 1.f;
  int coln = l & 15;
#pragma unroll
  for (int ct = 0; ct < NCT; ++ct) {
    int col = ct * 16 + coln;
    float bias = SCALE_DIS ? 0.f : ((ct == 0) ? b1[coln] : b2[coln]);
#pragma unroll
    for (int r = 0; r < 4; ++r) {
      int row = r0 + r;
      if (row < N) H[(size_t)row * DOUT + col] = bf1(acc[ct][r] * scale[r] + bias);
    }
  }
}

// ---- attention epilogue: s1/s2 from Ha[N,32] ----
__global__ __launch_bounds__(256) void k_att(const ushort* __restrict__ Ha,
                                             const float* __restrict__ aw,
                                             const float* __restrict__ attb,
                                             float* __restrict__ s1,
                                             float* __restrict__ s2, int N) {
  int n = blockIdx.x * 256 + threadIdx.x;
  if (n >= N) return;
  const uint32_t* h = (const uint32_t*)(Ha + (size_t)n * 32);
  float r1 = 0.f, r2 = 0.f;
#pragma unroll
  for (int q = 0; q < 8; ++q) {
    uint32_t u = h[q];
    r1 += fmaxf(bf_lo(u), 0.f) * aw[q * 2] + fmaxf(bf_hi(u), 0.f) * aw[q * 2 + 1];
  }
#pragma unroll
  for (int q = 0; q < 8; ++q) {
    uint32_t u = h[8 + q];
    r2 += fmaxf(bf_lo(u), 0.f) * aw[16 + q * 2] + fmaxf(bf_hi(u), 0.f) * aw[17 + q * 2];
  }
  s1[n] = r1;
  s2[n] = r2 + attb[0];
}

// ---- CSR build (row-range partitioned by blockIdx%8) ----
__global__ __launch_bounds__(256) void k_hist8(const int* __restrict__ row,
                                               int* __restrict__ counts, int E, int N) {
  int g = blockIdx.x & 7;
  int bj = blockIdx.x >> 3, nbj = gridDim.x >> 3;
  int lo = (int)(((long long)N * g) >> 3);
  int hi = (int)(((long long)N * (g + 1)) >> 3);
  for (int e = bj * 256 + threadIdx.x; e < E; e += nbj * 256) {
    int r = row[e];
    if (r >= lo && r < hi) atomicAdd(&counts[r], 1);
  }
}

__global__ __launch_bounds__(256) void k_blocksum(const int* __restrict__ counts,
                                                  int* __restrict__ bsum, int N) {
  __shared__ int sdata[256];
  int base = blockIdx.x * 1024;
  int s = 0;
#pragma unroll
  for (int k = 0; k < 4; k++) {
    int i = base + k * 256 + threadIdx.x;
    if (i < N) s += counts[i];
  }
  sdata[threadIdx.x] = s;
  __syncthreads();
  for (int off = 128; off > 0; off >>= 1) {
    if (threadIdx.x < off) sdata[threadIdx.x] += sdata[threadIdx.x + off];
    __syncthreads();
  }
  if (threadIdx.x == 0) bsum[blockIdx.x] = sdata[0];
}

__global__ __launch_bounds__(128) void k_scanpart(const int* __restrict__ bsum,
                                                  int* __restrict__ boff, int NB,
                                                  int* __restrict__ row_start, int N) {
  __shared__ int s[129];
  int t = threadIdx.x;
  s[t] = (t < NB) ? bsum[t] : 0;
  __syncthreads();
  if (t == 0) {
    int r = 0;
    for (int b = 0; b < NB; b++) { int v = s[b]; s[b] = r; r += v; }
    row_start[N] = r;  // == E
  }
  __syncthreads();
  if (t < NB) boff[t] = s[t];
}

__global__ __launch_bounds__(256) void k_scanblk(const int* __restrict__ counts,
                                                 const int* __restrict__ boff,
                                                 int* __restrict__ row_start, int N) {
  __shared__ int warp_sums[4];
  int tid = threadIdx.x, lane = tid & 63, wid = tid >> 6;
  int base = blockIdx.x * 1024;
  int i0 = base + tid * 4;
  int c0, c1, c2, c3;
  if (i0 + 3 < N) {
    int4 v = *(const int4*)(counts + i0);
    c0 = v.x; c1 = v.y; c2 = v.z; c3 = v.w;
  } else {
    c0 = (i0 + 0 < N) ? counts[i0 + 0] : 0;
    c1 = (i0 + 1 < N) ? counts[i0 + 1] : 0;
    c2 = (i0 + 2 < N) ? counts[i0 + 2] : 0;
    c3 = (i0 + 3 < N) ? counts[i0 + 3] : 0;
  }
  int s = c0 + c1 + c2 + c3;
  int incl = s;
#pragma unroll
  for (int off = 1; off < 64; off <<= 1) {
    int v = __shfl_up(incl, off);
    if (lane >= off) incl += v;
  }
  if (lane == 63) warp_sums[wid] = incl;
  __syncthreads();
  int pre = 0;
  for (int w = 0; w < wid; w++) pre += warp_sums[w];
  int run = boff[blockIdx.x] + pre + incl - s;
  if (i0 + 0 < N) row_start[i0 + 0] = run; run += c0;
  if (i0 + 1 < N) row_start[i0 + 1] = run; run += c1;
  if (i0 + 2 < N) row_start[i0 + 2] = run; run += c2;
  if (i0 + 3 < N) row_start[i0 + 3] = run;
}

__global__ __launch_bounds__(256) void k_scatter8(const int* __restrict__ row,
                                                  const int* __restrict__ col,
                                                  const int* __restrict__ row_start,
                                                  int* __restrict__ counts,
                                                  int* __restrict__ csr_col, int E, int N) {
  int g = blockIdx.x & 7;
  int bj = blockIdx.x >> 3, nbj = gridDim.x >> 3;
  int lo = (int)(((long long)N * g) >> 3);
  int hi = (int)(((long long)N * (g + 1)) >> 3);
  for (int e = bj * 256 + threadIdx.x; e < E; e += nbj * 256) {
    int r = row[e];
    if (r >= lo && r < hi) {
      int c = col[e];
      int old = atomicSub(&counts[r], 1);  // deg -> 0; fills row backward
      csr_col[row_start[r] + old - 1] = c;
    }
  }
}

// ---- One wave per row: masked degree -> dis ----
__global__ __launch_bounds__(256) void k_dis(const int* __restrict__ rs,
                                             const int* __restrict__ csr_col,
                                             const float* __restrict__ s1,
                                             const float* __restrict__ s2,
                                             float* __restrict__ dis, int N) {
  int lane = threadIdx.x & 63, wid = threadIdx.x >> 6;
  int r = blockIdx.x * 4 + wid;
  if (r >= N) return;
  int start = rs[r], end = rs[r + 1];
  float s1r = s1[r];
  float sum = 0.f;
  for (int p = start + lane; p < end; p += 64) sum += maskfn(s1r + s2[csr_col[p]]);
#pragma unroll
  for (int off = 32; off > 0; off >>= 1) sum += __shfl_down(sum, off);
  if (lane == 0) dis[r] = rsqrtf(sum + 1.0f);
}

// ---- One wave per row, mask recomputed inline; optional bf16 output ----
template <int DOUT, bool RELU, bool OUT_BF16>
__global__ __launch_bounds__(256) void k_agg(const int* __restrict__ rs,
                                             const int* __restrict__ csr_col,
                                             const float* __restrict__ s1,
                                             const float* __restrict__ s2,
                                             const float* __restrict__ dis,
                                             const uint32_t* __restrict__ Hs,
                                             void* __restrict__ outv, int N) {
  constexpr int LPE = DOUT / 4;
  constexpr int EPI = 64 / LPE;
  int lane = threadIdx.x & 63, wid = threadIdx.x >> 6;
  int r = blockIdx.x * 4 + wid;
  if (r >= N) return;
  int start = rs[r], end = rs[r + 1];
  float s1r = s1[r];
  int sub = lane / LPE;
  int fl = lane & (LPE - 1);
  float a0 = 0.f, a1 = 0.f, a2 = 0.f, a3 = 0.f;
  {  // self term (mask == 1), only in group 0
    uint2 u = *(const uint2*)(Hs + (size_t)r * (DOUT / 2) + fl * 2);
    if (sub == 0) { a0 = bf_lo(u.x); a1 = bf_hi(u.x); a2 = bf_lo(u.y); a3 = bf_hi(u.y); }
  }
  int p = start;
  for (; p + 2 * EPI <= end; p += 2 * EPI) {
    int eA = p + sub, eB = p + EPI + sub;
    int cA = csr_col[eA], cB = csr_col[eB];
    float mA = maskfn(s1r + s2[cA]);
    float mB = maskfn(s1r + s2[cB]);
    uint2 uA = *(const uint2*)(Hs + (size_t)cA * (DOUT / 2) + fl * 2);
    uint2 uB = *(const uint2*)(Hs + (size_t)cB * (DOUT / 2) + fl * 2);
    a0 = fmaf(mA, bf_lo(uA.x), a0); a1 = fmaf(mA, bf_hi(uA.x), a1);
    a2 = fmaf(mA, bf_lo(uA.y), a2); a3 = fmaf(mA, bf_hi(uA.y), a3);
    a0 = fmaf(mB, bf_lo(uB.x), a0); a1 = fmaf(mB, bf_hi(uB.x), a1);
    a2 = fmaf(mB, bf_lo(uB.y), a2); a3 = fmaf(mB, bf_hi(uB.y), a3);
  }
  for (; p < end; p += EPI) {
    int e = p + sub;
    bool v = e < end;
    int c = v ? csr_col[e] : r;
    float m = v ? maskfn(s1r + s2[c]) : 0.f;
    uint2 u = *(const uint2*)(Hs + (size_t)c * (DOUT / 2) + fl * 2);
    a0 = fmaf(m, bf_lo(u.x), a0); a1 = fmaf(m, bf_hi(u.x), a1);
    a2 = fmaf(m, bf_lo(u.y), a2); a3 = fmaf(m, bf_hi(u.y), a3);
  }
#pragma unroll
  for (int off = LPE; off < 64; off <<= 1) {
    a0 += __shfl_xor(a0, off); a1 += __shfl_xor(a1, off);
    a2 += __shfl_xor(a2, off); a3 += __shfl_xor(a3, off);
  }
  if (lane < LPE) {
    float dr = dis[r];
    float4 o = make_float4(dr * a0, dr * a1, dr * a2, dr * a3);
    if (RELU) {
      o.x = fmaxf(o.x, 0.f); o.y = fmaxf(o.y, 0.f);
      o.z = fmaxf(o.z, 0.f); o.w = fmaxf(o.w, 0.f);
    }
    if (OUT_BF16) {
      uint2 u = make_uint2(pack_bf2(o.x, o.y), pack_bf2(o.z, o.w));
      *(uint2*)((uint32_t*)outv + (size_t)r * (DOUT / 2) + fl * 2) = u;
    } else {
      *(float4*)((float*)outv + (size_t)r * DOUT + fl * 4) = o;
    }
  }
}

extern "C" void kernel_launch(void* const* d_in, const int* in_sizes, int n_in,
                              void* d_out, int out_size, void* d_ws, size_t ws_size,
                              hipStream_t stream) {
  const float* x      = (const float*)d_in[0];
  const int*   row    = (const int*)d_in[1];
  const int*   col    = (const int*)d_in[2];
  const float* nb_w   = (const float*)d_in[3];
  const float* nb_b   = (const float*)d_in[4];
  const float* self_w = (const float*)d_in[5];
  const float* self_b = (const float*)d_in[6];
  const float* att_w  = (const float*)d_in[7];
  const float* att_b  = (const float*)d_in[8];
  const float* w0     = (const float*)d_in[9];
  const float* w1     = (const float*)d_in[10];
  float* out = (float*)d_out;

  const int N = in_sizes[0] / 128;
  const int E = in_sizes[1];

  char* wp = (char*)d_ws;
  auto alloc = [&](size_t bytes) -> void* {
    void* q = (void*)wp;
    wp += (bytes + 255) & ~(size_t)255;
    return q;
  };
  int*      counts    = (int*)alloc((size_t)N * 4);   // degree, then scatter cursor
  int*      row_start = (int*)alloc((size_t)(N + 1) * 4);
  int*      bsum      = (int*)alloc(512);
  int*      boff      = (int*)alloc(512);
  int*      csr_col   = (int*)alloc((size_t)E * 4);
  float*    s1        = (float*)alloc((size_t)N * 4);
  float*    s2        = (float*)alloc((size_t)N * 4);
  float*    dis       = (float*)alloc((size_t)N * 4);
  ushort*   xb        = (ushort*)alloc((size_t)N * 128 * 2);  // layer0 X; reused as x1b
  ushort*   Ha        = (ushort*)alloc((size_t)N * 32 * 2);
  ushort*   Hs        = (ushort*)alloc((size_t)N * 128 * 2);
  ushort*   w0b       = (ushort*)alloc(16384 * 2);
  ushort*   w1b       = (ushort*)alloc(8192 * 2);
  ushort*   aW0       = (ushort*)alloc(4096 * 2);
  ushort*   aW1       = (ushort*)alloc(4096 * 2);

  const int NB = (N + 1023) / 1024;  // 98 (<=128)
  const int gw = (N + 3) / 4;
  const int gp = (N + 255) / 256;
  const int gm = (N + 63) / 64;
  const int gc = (N * 16 + 255) / 256;  // n8 = N*128/8 = N*16

  // ---- CSR build + bf16 conversions ----
  hipMemsetAsync(counts, 0, (size_t)N * 4, stream);
  k_hist8<<<2048, 256, 0, stream>>>(row, counts, E, N);
  k_blocksum<<<NB, 256, 0, stream>>>(counts, bsum, N);
  k_scanpart<<<1, 128, 0, stream>>>(bsum, boff, NB, row_start, N);
  k_scanblk<<<NB, 256, 0, stream>>>(counts, boff, row_start, N);
  k_scatter8<<<2048, 256, 0, stream>>>(row, col, row_start, counts, csr_col, E, N);
  k_cvt<<<gc, 256, 0, stream>>>(x, xb, N * 16);
  k_wpack<<<128, 256, 0, stream>>>(w0, w1, nb_w, self_w, w0b, w1b, aW0, aW1);

  // ---- layer 0: din=128, dout=128, relu; x1b (bf16) aliases xb ----
  k_mgemm<32, false><<<gm, 256, 0, stream>>>(xb, aW0, nullptr, nb_b, self_b, Ha, N);
  k_att<<<gp, 256, 0, stream>>>(Ha, att_w, att_b, s1, s2, N);
  k_dis<<<gw, 256, 0, stream>>>(row_start, csr_col, s1, s2, dis, N);
  k_mgemm<128, true><<<gm, 256, 0, stream>>>(xb, w0b, dis, nullptr, nullptr, Hs, N);
  k_agg<128, true, true><<<gw, 256, 0, stream>>>(row_start, csr_col, s1, s2, dis,
                                                 (const uint32_t*)Hs, xb, N);

  // ---- layer 1: din=128, dout=64, identity ----
  k_mgemm<32, false><<<gm, 256, 0, stream>>>(xb, aW1, nullptr, nb_b + 16, self_b + 16, Ha, N);
  k_att<<<gp, 256, 0, stream>>>(Ha, att_w + 32, att_b + 1, s1, s2, N);
  k_dis<<<gw, 256, 0, stream>>>(row_start, csr_col, s1, s2, dis, N);
  k_mgemm<64, true><<<gm, 256, 0, stream>>>(xb, w1b, dis, nullptr, nullptr, Hs, N);
  k_agg<64, false, false><<<gw, 256, 0, stream>>>(row_start, csr_col, s1, s2, dis,
                                                  (const uint32_t*)Hs, out, N);
}

// Round 8
// 487.976 us; speedup vs baseline: 1.4821x; 1.0224x over previous
//
#include <hip/hip_runtime.h>

// PTDNet-GCN eval forward.
//  - L=2 hard-concrete samples identical in eval -> compute once.
//  - Edge MLP factors into per-node scalars s1/s2; all matmuls (att 128->16x2,
//    GCN 128->{128,64}) run as bf16 MFMA 16x16x32, A from global bf16 rows,
//    B pre-packed into per-lane fragments.
//  - CSR build: hist/scatter partitioned into 8 row-ranges by blockIdx%8 (~XCD)
//    so random atomics/writes stay in one XCD's L2 (fixes 17x write amplif.).
//  - k_mask computes each edge's hard-concrete mask ONCE (stores f32) + dis.
//    r7 recomputed maskfn in k_agg per-lane (32x redundant exp/rcp -> VALUBusy
//    65%); materializing costs 6.4MB stream vs ~48 wasted cyc/iter. [r7 PMC]
//  - Hs bf16, pre-scaled by dis[c] in mgemm epilogue -> agg edge work = gather+fma.

typedef __attribute__((ext_vector_type(8))) short bf16x8;
typedef __attribute__((ext_vector_type(4))) float f32x4;

__device__ inline float bf_lo(uint32_t u) { return __uint_as_float(u << 16); }
__device__ inline float bf_hi(uint32_t u) { return __uint_as_float(u & 0xffff0000u); }
__device__ inline ushort bf1(float x) {  // RTNE
  uint32_t b = __float_as_uint(x);
  return (ushort)((b + 0x7fffu + ((b >> 16) & 1u)) >> 16);
}
__device__ inline uint32_t pack_bf2(float x, float y) {
  return (uint32_t)bf1(x) | ((uint32_t)bf1(y) << 16);
}
__device__ inline float maskfn(float logit) {
  float g = 1.f / (1.f + __expf(-logit));
  return fminf(fmaxf(fmaf(g, 1.2f, -0.1f), 0.f), 1.f);  // ZETA-GAMMA=1.2, GAMMA=-0.1
}

// ---- f32 -> bf16 row conversion (8 elems/thread) ----
__global__ __launch_bounds__(256) void k_cvt(const float* __restrict__ X,
                                             ushort* __restrict__ Xb, int n8) {
  int i = blockIdx.x * 256 + threadIdx.x;
  if (i >= n8) return;
  const float4* s = (const float4*)(X + (size_t)i * 8);
  float4 v0 = s[0], v1 = s[1];
  uint4 o;
  o.x = pack_bf2(v0.x, v0.y); o.y = pack_bf2(v0.z, v0.w);
  o.z = pack_bf2(v1.x, v1.y); o.w = pack_bf2(v1.z, v1.w);
  *(uint4*)(Xb + (size_t)i * 8) = o;
}

// ---- pack all weight matrices into MFMA B-fragment order ----
// frag = ((ct*4+g)*64+l)*8+j stores bf16( W[k][col] ), k=g*32+(l>>4)*8+j,
// col=ct*16+(l&15). w0b:16384, w1b:8192, aW{0,1}:4096 (ct0=nb_w, ct1=self_w).
__global__ __launch_bounds__(256) void k_wpack(const float* __restrict__ w0,
                                               const float* __restrict__ w1,
                                               const float* __restrict__ nbw,
                                               const float* __restrict__ sfw,
                                               ushort* __restrict__ w0b,
                                               ushort* __restrict__ w1b,
                                               ushort* __restrict__ aW0,
                                               ushort* __restrict__ aW1) {
  int t = blockIdx.x * 256 + threadIdx.x;
  if (t < 16384) {
    int j = t & 7, l = (t >> 3) & 63, g = (t >> 9) & 3, ct = t >> 11;
    int k = g * 32 + (l >> 4) * 8 + j;
    w0b[t] = bf1(w0[k * 128 + ct * 16 + (l & 15)]);
  } else if (t < 24576) {
    int rem = t - 16384;
    int j = rem & 7, l = (rem >> 3) & 63, g = (rem >> 9) & 3, ct = rem >> 11;
    int k = g * 32 + (l >> 4) * 8 + j;
    w1b[rem] = bf1(w1[k * 64 + ct * 16 + (l & 15)]);
  } else if (t < 32768) {
    int rem = t - 24576;            // [0, 8192)
    int layer = rem >> 12;          // 4096 per layer
    int full = rem & 4095;          // ct(1b) | g(2b) | l(6b) | j(3b)
    int j = full & 7, l = (full >> 3) & 63, g = (full >> 9) & 3, ct = full >> 11;
    int k = g * 32 + (l >> 4) * 8 + j;
    const float* src = (ct == 0 ? nbw : sfw) + layer * 2048;  // [128][16] slab
    ushort* dst = (layer == 0 ? aW0 : aW1);
    dst[full] = bf1(src[k * 16 + (l & 15)]);
  }
}

// ---- MFMA GEMM: H[N,DOUT](bf16) = Xb[N,128] @ Wp, epilogue dis-scale or bias ----
template <int DOUT, bool SCALE_DIS>
__global__ __launch_bounds__(256) void k_mgemm(const ushort* __restrict__ Xb,
                                               const ushort* __restrict__ Wp,
                                               const float* __restrict__ dis,
                                               const float* __restrict__ b1,
                                               const float* __restrict__ b2,
                                               ushort* __restrict__ H, int N) {
  constexpr int NCT = DOUT / 16;
  int tid = threadIdx.x, w = tid >> 6, l = tid & 63;
  int n0 = blockIdx.x * 64 + w * 16;
  int arow = n0 + (l & 15);
  if (arow >= N) arow = N - 1;
  const ushort* xr = Xb + (size_t)arow * 128 + (l >> 4) * 8;
  bf16x8 a[4];
#pragma unroll
  for (int g = 0; g < 4; ++g) a[g] = *(const bf16x8*)(xr + g * 32);
  f32x4 acc[NCT];
#pragma unroll
  for (int ct = 0; ct < NCT; ++ct) acc[ct] = (f32x4){0.f, 0.f, 0.f, 0.f};
  const ushort* wp = Wp + l * 8;
#pragma unroll
  for (int ct = 0; ct < NCT; ++ct) {
#pragma unroll
    for (int g = 0; g < 4; ++g) {
      bf16x8 b = *(const bf16x8*)(wp + (size_t)(ct * 4 + g) * 512);
      acc[ct] = __builtin_amdgcn_mfma_f32_16x16x32_bf16(a[g], b, acc[ct], 0, 0, 0);
    }
  }
  int r0 = n0 + (l >> 4) * 4;  // C/D: col=lane&15, row=(lane>>4)*4+reg [m89]
  float scale[4];
#pragma unroll
  for (int r = 0; r < 4; ++r)
    scale[r] = SCALE_DIS ? ((r0 + r < N) ? dis[r0 + r] : 0.f) : 1.f;
  int coln = l & 15;
#pragma unroll
  for (int ct = 0; ct < NCT; ++ct) {
    int col = ct * 16 + coln;
    float bias = SCALE_DIS ? 0.f : ((ct == 0) ? b1[coln] : b2[coln]);
#pragma unroll
    for (int r = 0; r < 4; ++r) {
      int row = r0 + r;
      if (row < N) H[(size_t)row * DOUT + col] = bf1(acc[ct][r] * scale[r] + bias);
    }
  }
}

// ---- attention epilogue: s1/s2 from Ha[N,32] ----
__global__ __launch_bounds__(256) void k_att(const ushort* __restrict__ Ha,
                                             const float* __restrict__ aw,
                                             const float* __restrict__ attb,
                                             float* __restrict__ s1,
                                             float* __restrict__ s2, int N) {
  int n = blockIdx.x * 256 + threadIdx.x;
  if (n >= N) return;
  const uint32_t* h = (const uint32_t*)(Ha + (size_t)n * 32);
  float r1 = 0.f, r2 = 0.f;
#pragma unroll
  for (int q = 0; q < 8; ++q) {
    uint32_t u = h[q];
    r1 += fmaxf(bf_lo(u), 0.f) * aw[q * 2] + fmaxf(bf_hi(u), 0.f) * aw[q * 2 + 1];
  }
#pragma unroll
  for (int q = 0; q < 8; ++q) {
    uint32_t u = h[8 + q];
    r2 += fmaxf(bf_lo(u), 0.f) * aw[16 + q * 2] + fmaxf(bf_hi(u), 0.f) * aw[17 + q * 2];
  }
  s1[n] = r1;
  s2[n] = r2 + attb[0];
}

// ---- CSR build (row-range partitioned by blockIdx%8) ----
__global__ __launch_bounds__(256) void k_hist8(const int* __restrict__ row,
                                               int* __restrict__ counts, int E, int N) {
  int g = blockIdx.x & 7;
  int bj = blockIdx.x >> 3, nbj = gridDim.x >> 3;
  int lo = (int)(((long long)N * g) >> 3);
  int hi = (int)(((long long)N * (g + 1)) >> 3);
  for (int e = bj * 256 + threadIdx.x; e < E; e += nbj * 256) {
    int r = row[e];
    if (r >= lo && r < hi) atomicAdd(&counts[r], 1);
  }
}

__global__ __launch_bounds__(256) void k_blocksum(const int* __restrict__ counts,
                                                  int* __restrict__ bsum, int N) {
  __shared__ int sdata[256];
  int base = blockIdx.x * 1024;
  int s = 0;
#pragma unroll
  for (int k = 0; k < 4; k++) {
    int i = base + k * 256 + threadIdx.x;
    if (i < N) s += counts[i];
  }
  sdata[threadIdx.x] = s;
  __syncthreads();
  for (int off = 128; off > 0; off >>= 1) {
    if (threadIdx.x < off) sdata[threadIdx.x] += sdata[threadIdx.x + off];
    __syncthreads();
  }
  if (threadIdx.x == 0) bsum[blockIdx.x] = sdata[0];
}

__global__ __launch_bounds__(128) void k_scanpart(const int* __restrict__ bsum,
                                                  int* __restrict__ boff, int NB,
                                                  int* __restrict__ row_start, int N) {
  __shared__ int s[129];
  int t = threadIdx.x;
  s[t] = (t < NB) ? bsum[t] : 0;
  __syncthreads();
  if (t == 0) {
    int r = 0;
    for (int b = 0; b < NB; b++) { int v = s[b]; s[b] = r; r += v; }
    row_start[N] = r;  // == E
  }
  __syncthreads();
  if (t < NB) boff[t] = s[t];
}

__global__ __launch_bounds__(256) void k_scanblk(const int* __restrict__ counts,
                                                 const int* __restrict__ boff,
                                                 int* __restrict__ row_start, int N) {
  __shared__ int warp_sums[4];
  int tid = threadIdx.x, lane = tid & 63, wid = tid >> 6;
  int base = blockIdx.x * 1024;
  int i0 = base + tid * 4;
  int c0, c1, c2, c3;
  if (i0 + 3 < N) {
    int4 v = *(const int4*)(counts + i0);
    c0 = v.x; c1 = v.y; c2 = v.z; c3 = v.w;
  } else {
    c0 = (i0 + 0 < N) ? counts[i0 + 0] : 0;
    c1 = (i0 + 1 < N) ? counts[i0 + 1] : 0;
    c2 = (i0 + 2 < N) ? counts[i0 + 2] : 0;
    c3 = (i0 + 3 < N) ? counts[i0 + 3] : 0;
  }
  int s = c0 + c1 + c2 + c3;
  int incl = s;
#pragma unroll
  for (int off = 1; off < 64; off <<= 1) {
    int v = __shfl_up(incl, off);
    if (lane >= off) incl += v;
  }
  if (lane == 63) warp_sums[wid] = incl;
  __syncthreads();
  int pre = 0;
  for (int w = 0; w < wid; w++) pre += warp_sums[w];
  int run = boff[blockIdx.x] + pre + incl - s;
  if (i0 + 0 < N) row_start[i0 + 0] = run; run += c0;
  if (i0 + 1 < N) row_start[i0 + 1] = run; run += c1;
  if (i0 + 2 < N) row_start[i0 + 2] = run; run += c2;
  if (i0 + 3 < N) row_start[i0 + 3] = run;
}

__global__ __launch_bounds__(256) void k_scatter8(const int* __restrict__ row,
                                                  const int* __restrict__ col,
                                                  const int* __restrict__ row_start,
                                                  int* __restrict__ counts,
                                                  int* __restrict__ csr_col, int E, int N) {
  int g = blockIdx.x & 7;
  int bj = blockIdx.x >> 3, nbj = gridDim.x >> 3;
  int lo = (int)(((long long)N * g) >> 3);
  int hi = (int)(((long long)N * (g + 1)) >> 3);
  for (int e = bj * 256 + threadIdx.x; e < E; e += nbj * 256) {
    int r = row[e];
    if (r >= lo && r < hi) {
      int c = col[e];
      int old = atomicSub(&counts[r], 1);  // deg -> 0; fills row backward
      csr_col[row_start[r] + old - 1] = c;
    }
  }
}

// ---- One wave per row: per-edge mask (stored once) + dis ----
__global__ __launch_bounds__(256) void k_mask(const int* __restrict__ rs,
                                              const int* __restrict__ csr_col,
                                              const float* __restrict__ s1,
                                              const float* __restrict__ s2,
                                              float* __restrict__ mask,
                                              float* __restrict__ dis, int N) {
  int lane = threadIdx.x & 63, wid = threadIdx.x >> 6;
  int r = blockIdx.x * 4 + wid;
  if (r >= N) return;
  int start = rs[r], end = rs[r + 1];
  float s1r = s1[r];
  float sum = 0.f;
  for (int p = start + lane; p < end; p += 64) {
    float m = maskfn(s1r + s2[csr_col[p]]);
    mask[p] = m;
    sum += m;
  }
#pragma unroll
  for (int off = 32; off > 0; off >>= 1) sum += __shfl_down(sum, off);
  if (lane == 0) dis[r] = rsqrtf(sum + 1.0f);
}

// ---- One wave per row: out[r] = act( dis[r] * (sum_e mask_e*Hs[col_e] + Hs[r]) ) ----
template <int DOUT, bool RELU, bool OUT_BF16>
__global__ __launch_bounds__(256) void k_agg(const int* __restrict__ rs,
                                             const int* __restrict__ csr_col,
                                             const float* __restrict__ mask,
                                             const float* __restrict__ dis,
                                             const uint32_t* __restrict__ Hs,
                                             void* __restrict__ outv, int N) {
  constexpr int LPE = DOUT / 4;
  constexpr int EPI = 64 / LPE;
  int lane = threadIdx.x & 63, wid = threadIdx.x >> 6;
  int r = blockIdx.x * 4 + wid;
  if (r >= N) return;
  int start = rs[r], end = rs[r + 1];
  int sub = lane / LPE;
  int fl = lane & (LPE - 1);
  float a0 = 0.f, a1 = 0.f, a2 = 0.f, a3 = 0.f;
  {  // self term (mask == 1), only in group 0
    uint2 u = *(const uint2*)(Hs + (size_t)r * (DOUT / 2) + fl * 2);
    if (sub == 0) { a0 = bf_lo(u.x); a1 = bf_hi(u.x); a2 = bf_lo(u.y); a3 = bf_hi(u.y); }
  }
  int p = start;
  for (; p + 2 * EPI <= end; p += 2 * EPI) {
    int eA = p + sub, eB = p + EPI + sub;
    int cA = csr_col[eA], cB = csr_col[eB];
    float mA = mask[eA], mB = mask[eB];
    uint2 uA = *(const uint2*)(Hs + (size_t)cA * (DOUT / 2) + fl * 2);
    uint2 uB = *(const uint2*)(Hs + (size_t)cB * (DOUT / 2) + fl * 2);
    a0 = fmaf(mA, bf_lo(uA.x), a0); a1 = fmaf(mA, bf_hi(uA.x), a1);
    a2 = fmaf(mA, bf_lo(uA.y), a2); a3 = fmaf(mA, bf_hi(uA.y), a3);
    a0 = fmaf(mB, bf_lo(uB.x), a0); a1 = fmaf(mB, bf_hi(uB.x), a1);
    a2 = fmaf(mB, bf_lo(uB.y), a2); a3 = fmaf(mB, bf_hi(uB.y), a3);
  }
  for (; p < end; p += EPI) {
    int e = p + sub;
    bool v = e < end;
    int c = v ? csr_col[e] : r;
    float m = v ? mask[e] : 0.f;
    uint2 u = *(const uint2*)(Hs + (size_t)c * (DOUT / 2) + fl * 2);
    a0 = fmaf(m, bf_lo(u.x), a0); a1 = fmaf(m, bf_hi(u.x), a1);
    a2 = fmaf(m, bf_lo(u.y), a2); a3 = fmaf(m, bf_hi(u.y), a3);
  }
#pragma unroll
  for (int off = LPE; off < 64; off <<= 1) {
    a0 += __shfl_xor(a0, off); a1 += __shfl_xor(a1, off);
    a2 += __shfl_xor(a2, off); a3 += __shfl_xor(a3, off);
  }
  if (lane < LPE) {
    float dr = dis[r];
    float4 o = make_float4(dr * a0, dr * a1, dr * a2, dr * a3);
    if (RELU) {
      o.x = fmaxf(o.x, 0.f); o.y = fmaxf(o.y, 0.f);
      o.z = fmaxf(o.z, 0.f); o.w = fmaxf(o.w, 0.f);
    }
    if (OUT_BF16) {
      uint2 u = make_uint2(pack_bf2(o.x, o.y), pack_bf2(o.z, o.w));
      *(uint2*)((uint32_t*)outv + (size_t)r * (DOUT / 2) + fl * 2) = u;
    } else {
      *(float4*)((float*)outv + (size_t)r * DOUT + fl * 4) = o;
    }
  }
}

extern "C" void kernel_launch(void* const* d_in, const int* in_sizes, int n_in,
                              void* d_out, int out_size, void* d_ws, size_t ws_size,
                              hipStream_t stream) {
  const float* x      = (const float*)d_in[0];
  const int*   row    = (const int*)d_in[1];
  const int*   col    = (const int*)d_in[2];
  const float* nb_w   = (const float*)d_in[3];
  const float* nb_b   = (const float*)d_in[4];
  const float* self_w = (const float*)d_in[5];
  const float* self_b = (const float*)d_in[6];
  const float* att_w  = (const float*)d_in[7];
  const float* att_b  = (const float*)d_in[8];
  const float* w0     = (const float*)d_in[9];
  const float* w1     = (const float*)d_in[10];
  float* out = (float*)d_out;

  const int N = in_sizes[0] / 128;
  const int E = in_sizes[1];

  char* wp = (char*)d_ws;
  auto alloc = [&](size_t bytes) -> void* {
    void* q = (void*)wp;
    wp += (bytes + 255) & ~(size_t)255;
    return q;
  };
  int*      counts    = (int*)alloc((size_t)N * 4);   // degree, then scatter cursor
  int*      row_start = (int*)alloc((size_t)(N + 1) * 4);
  int*      bsum      = (int*)alloc(512);
  int*      boff      = (int*)alloc(512);
  int*      csr_col   = (int*)alloc((size_t)E * 4);
  float*    mask      = (float*)alloc((size_t)E * 4);
  float*    s1        = (float*)alloc((size_t)N * 4);
  float*    s2        = (float*)alloc((size_t)N * 4);
  float*    dis       = (float*)alloc((size_t)N * 4);
  ushort*   xb        = (ushort*)alloc((size_t)N * 128 * 2);  // layer0 X; reused as x1b
  ushort*   Ha        = (ushort*)alloc((size_t)N * 32 * 2);
  ushort*   Hs        = (ushort*)alloc((size_t)N * 128 * 2);
  ushort*   w0b       = (ushort*)alloc(16384 * 2);
  ushort*   w1b       = (ushort*)alloc(8192 * 2);
  ushort*   aW0       = (ushort*)alloc(4096 * 2);
  ushort*   aW1       = (ushort*)alloc(4096 * 2);

  const int NB = (N + 1023) / 1024;  // 98 (<=128)
  const int gw = (N + 3) / 4;
  const int gp = (N + 255) / 256;
  const int gm = (N + 63) / 64;
  const int gc = (N * 16 + 255) / 256;  // n8 = N*128/8 = N*16

  // ---- CSR build + bf16 conversions ----
  hipMemsetAsync(counts, 0, (size_t)N * 4, stream);
  k_hist8<<<2048, 256, 0, stream>>>(row, counts, E, N);
  k_blocksum<<<NB, 256, 0, stream>>>(counts, bsum, N);
  k_scanpart<<<1, 128, 0, stream>>>(bsum, boff, NB, row_start, N);
  k_scanblk<<<NB, 256, 0, stream>>>(counts, boff, row_start, N);
  k_scatter8<<<2048, 256, 0, stream>>>(row, col, row_start, counts, csr_col, E, N);
  k_cvt<<<gc, 256, 0, stream>>>(x, xb, N * 16);
  k_wpack<<<128, 256, 0, stream>>>(w0, w1, nb_w, self_w, w0b, w1b, aW0, aW1);

  // ---- layer 0: din=128, dout=128, relu; x1b (bf16) aliases xb ----
  k_mgemm<32, false><<<gm, 256, 0, stream>>>(xb, aW0, nullptr, nb_b, self_b, Ha, N);
  k_att<<<gp, 256, 0, stream>>>(Ha, att_w, att_b, s1, s2, N);
  k_mask<<<gw, 256, 0, stream>>>(row_start, csr_col, s1, s2, mask, dis, N);
  k_mgemm<128, true><<<gm, 256, 0, stream>>>(xb, w0b, dis, nullptr, nullptr, Hs, N);
  k_agg<128, true, true><<<gw, 256, 0, stream>>>(row_start, csr_col, mask, dis,
                                                 (const uint32_t*)Hs, xb, N);

  // ---- layer 1: din=128, dout=64, identity ----
  k_mgemm<32, false><<<gm, 256, 0, stream>>>(xb, aW1, nullptr, nb_b + 16, self_b + 16, Ha, N);
  k_att<<<gp, 256, 0, stream>>>(Ha, att_w + 32, att_b + 1, s1, s2, N);
  k_mask<<<gw, 256, 0, stream>>>(row_start, csr_col, s1, s2, mask, dis, N);
  k_mgemm<64, true><<<gm, 256, 0, stream>>>(xb, w1b, dis, nullptr, nullptr, Hs, N);
  k_agg<64, false, false><<<gw, 256, 0, stream>>>(row_start, csr_col, mask, dis,
                                                  (const uint32_t*)Hs, out, N);
}

// Round 9
// 445.919 us; speedup vs baseline: 1.6219x; 1.0943x over previous
//
#include <hip/hip_runtime.h>

// PTDNet-GCN eval forward.
//  - L=2 hard-concrete samples identical in eval -> compute once.
//  - Edge MLP factors into per-node scalars s1/s2; att MLP fused into one MFMA
//    kernel (k_matt: gemm + relu-dot epilogue via shfl reduce, no Ha buffer).
//  - GCN matmuls: bf16 MFMA 16x16x32, A from global bf16 rows, B pre-packed.
//  - CSR build: hist/scatter partitioned into 8 row-ranges by blockIdx%8 (~XCD).
//  - k_mask: 4 rows/wave (16 lanes each), mask stored once (r7: inline recompute
//    was 32x-redundant VALU; r8: 64-lane/row left 75% lanes idle).
//  - k_agg: 16(8) lanes/edge, uint4 gathers, 2 edges in flight per group
//    (r8 PMC: VALU 42%/HBM 38%/occ 72% => latency-bound, needed deeper MLP).
//  - Hs bf16 pre-scaled by dis[c] in mgemm epilogue.

typedef __attribute__((ext_vector_type(8))) short bf16x8;
typedef __attribute__((ext_vector_type(4))) float f32x4;

__device__ inline float bf_lo(uint32_t u) { return __uint_as_float(u << 16); }
__device__ inline float bf_hi(uint32_t u) { return __uint_as_float(u & 0xffff0000u); }
__device__ inline ushort bf1(float x) {  // RTNE
  uint32_t b = __float_as_uint(x);
  return (ushort)((b + 0x7fffu + ((b >> 16) & 1u)) >> 16);
}
__device__ inline uint32_t pack_bf2(float x, float y) {
  return (uint32_t)bf1(x) | ((uint32_t)bf1(y) << 16);
}
__device__ inline float maskfn(float logit) {
  float g = 1.f / (1.f + __expf(-logit));
  return fminf(fmaxf(fmaf(g, 1.2f, -0.1f), 0.f), 1.f);  // ZETA-GAMMA=1.2, GAMMA=-0.1
}

// ---- f32 -> bf16 row conversion (8 elems/thread) ----
__global__ __launch_bounds__(256) void k_cvt(const float* __restrict__ X,
                                             ushort* __restrict__ Xb, int n8) {
  int i = blockIdx.x * 256 + threadIdx.x;
  if (i >= n8) return;
  const float4* s = (const float4*)(X + (size_t)i * 8);
  float4 v0 = s[0], v1 = s[1];
  uint4 o;
  o.x = pack_bf2(v0.x, v0.y); o.y = pack_bf2(v0.z, v0.w);
  o.z = pack_bf2(v1.x, v1.y); o.w = pack_bf2(v1.z, v1.w);
  *(uint4*)(Xb + (size_t)i * 8) = o;
}

// ---- pack all weight matrices into MFMA B-fragment order ----
// frag = ((ct*4+g)*64+l)*8+j stores bf16( W[k][col] ), k=g*32+(l>>4)*8+j,
// col=ct*16+(l&15). w0b:16384, w1b:8192, aW{0,1}:4096 (ct0=nb_w, ct1=self_w).
__global__ __launch_bounds__(256) void k_wpack(const float* __restrict__ w0,
                                               const float* __restrict__ w1,
                                               const float* __restrict__ nbw,
                                               const float* __restrict__ sfw,
                                               ushort* __restrict__ w0b,
                                               ushort* __restrict__ w1b,
                                               ushort* __restrict__ aW0,
                                               ushort* __restrict__ aW1) {
  int t = blockIdx.x * 256 + threadIdx.x;
  if (t < 16384) {
    int j = t & 7, l = (t >> 3) & 63, g = (t >> 9) & 3, ct = t >> 11;
    int k = g * 32 + (l >> 4) * 8 + j;
    w0b[t] = bf1(w0[k * 128 + ct * 16 + (l & 15)]);
  } else if (t < 24576) {
    int rem = t - 16384;
    int j = rem & 7, l = (rem >> 3) & 63, g = (rem >> 9) & 3, ct = rem >> 11;
    int k = g * 32 + (l >> 4) * 8 + j;
    w1b[rem] = bf1(w1[k * 64 + ct * 16 + (l & 15)]);
  } else if (t < 32768) {
    int rem = t - 24576;            // [0, 8192)
    int layer = rem >> 12;          // 4096 per layer
    int full = rem & 4095;          // ct(1b) | g(2b) | l(6b) | j(3b)
    int j = full & 7, l = (full >> 3) & 63, g = (full >> 9) & 3, ct = full >> 11;
    int k = g * 32 + (l >> 4) * 8 + j;
    const float* src = (ct == 0 ? nbw : sfw) + layer * 2048;  // [128][16] slab
    ushort* dst = (layer == 0 ? aW0 : aW1);
    dst[full] = bf1(src[k * 16 + (l & 15)]);
  }
}

// ---- fused attention MLP: s1/s2 = rowwise relu(Xb@W+b) . aw  (MFMA + shfl) ----
__global__ __launch_bounds__(256) void k_matt(const ushort* __restrict__ Xb,
                                              const ushort* __restrict__ Wp,
                                              const float* __restrict__ b1,
                                              const float* __restrict__ b2,
                                              const float* __restrict__ aw,
                                              const float* __restrict__ attb,
                                              float* __restrict__ s1,
                                              float* __restrict__ s2, int N) {
  int tid = threadIdx.x, w = tid >> 6, l = tid & 63;
  int n0 = blockIdx.x * 64 + w * 16;
  int arow = n0 + (l & 15);
  if (arow >= N) arow = N - 1;
  const ushort* xr = Xb + (size_t)arow * 128 + (l >> 4) * 8;
  bf16x8 a[4];
#pragma unroll
  for (int g = 0; g < 4; ++g) a[g] = *(const bf16x8*)(xr + g * 32);
  f32x4 acc0 = {0.f, 0.f, 0.f, 0.f}, acc1 = acc0;
  const ushort* wp = Wp + l * 8;
#pragma unroll
  for (int g = 0; g < 4; ++g) {
    bf16x8 b0 = *(const bf16x8*)(wp + (size_t)g * 512);
    bf16x8 b1f = *(const bf16x8*)(wp + (size_t)(4 + g) * 512);
    acc0 = __builtin_amdgcn_mfma_f32_16x16x32_bf16(a[g], b0, acc0, 0, 0, 0);
    acc1 = __builtin_amdgcn_mfma_f32_16x16x32_bf16(a[g], b1f, acc1, 0, 0, 0);
  }
  int coln = l & 15;
  float awn = aw[coln], aws = aw[16 + coln];
  float bb1 = b1[coln], bb2 = b2[coln];
  float v1[4], v2[4];
#pragma unroll
  for (int r = 0; r < 4; ++r) {
    v1[r] = fmaxf(acc0[r] + bb1, 0.f) * awn;
    v2[r] = fmaxf(acc1[r] + bb2, 0.f) * aws;
  }
#pragma unroll
  for (int off = 1; off < 16; off <<= 1) {
#pragma unroll
    for (int r = 0; r < 4; ++r) {
      v1[r] += __shfl_xor(v1[r], off);
      v2[r] += __shfl_xor(v2[r], off);
    }
  }
  if (coln == 0) {
    int r0 = n0 + (l >> 4) * 4;  // C/D: col=lane&15, row=(lane>>4)*4+reg [m89]
    float ab = attb[0];
#pragma unroll
    for (int r = 0; r < 4; ++r) {
      int row = r0 + r;
      if (row < N) { s1[row] = v1[r]; s2[row] = v2[r] + ab; }
    }
  }
}

// ---- MFMA GEMM: H[N,DOUT](bf16) = dis[n] * (Xb[N,128] @ Wp)[n,:] ----
template <int DOUT>
__global__ __launch_bounds__(256) void k_mgemm(const ushort* __restrict__ Xb,
                                               const ushort* __restrict__ Wp,
                                               const float* __restrict__ dis,
                                               ushort* __restrict__ H, int N) {
  constexpr int NCT = DOUT / 16;
  int tid = threadIdx.x, w = tid >> 6, l = tid & 63;
  int n0 = blockIdx.x * 64 + w * 16;
  int arow = n0 + (l & 15);
  if (arow >= N) arow = N - 1;
  const ushort* xr = Xb + (size_t)arow * 128 + (l >> 4) * 8;
  bf16x8 a[4];
#pragma unroll
  for (int g = 0; g < 4; ++g) a[g] = *(const bf16x8*)(xr + g * 32);
  f32x4 acc[NCT];
#pragma unroll
  for (int ct = 0; ct < NCT; ++ct) acc[ct] = (f32x4){0.f, 0.f, 0.f, 0.f};
  const ushort* wp = Wp + l * 8;
#pragma unroll
  for (int ct = 0; ct < NCT; ++ct) {
#pragma unroll
    for (int g = 0; g < 4; ++g) {
      bf16x8 b = *(const bf16x8*)(wp + (size_t)(ct * 4 + g) * 512);
      acc[ct] = __builtin_amdgcn_mfma_f32_16x16x32_bf16(a[g], b, acc[ct], 0, 0, 0);
    }
  }
  int r0 = n0 + (l >> 4) * 4;  // C/D: col=lane&15, row=(lane>>4)*4+reg [m89]
  float scale[4];
#pragma unroll
  for (int r = 0; r < 4; ++r) scale[r] = (r0 + r < N) ? dis[r0 + r] : 0.f;
  int coln = l & 15;
#pragma unroll
  for (int ct = 0; ct < NCT; ++ct) {
    int col = ct * 16 + coln;
#pragma unroll
    for (int r = 0; r < 4; ++r) {
      int row = r0 + r;
      if (row < N) H[(size_t)row * DOUT + col] = bf1(acc[ct][r] * scale[r]);
    }
  }
}

// ---- CSR build (row-range partitioned by blockIdx%8) ----
__global__ __launch_bounds__(256) void k_hist8(const int* __restrict__ row,
                                               int* __restrict__ counts, int E, int N) {
  int g = blockIdx.x & 7;
  int bj = blockIdx.x >> 3, nbj = gridDim.x >> 3;
  int lo = (int)(((long long)N * g) >> 3);
  int hi = (int)(((long long)N * (g + 1)) >> 3);
  for (int e = bj * 256 + threadIdx.x; e < E; e += nbj * 256) {
    int r = row[e];
    if (r >= lo && r < hi) atomicAdd(&counts[r], 1);
  }
}

__global__ __launch_bounds__(256) void k_blocksum(const int* __restrict__ counts,
                                                  int* __restrict__ bsum, int N) {
  __shared__ int sdata[256];
  int base = blockIdx.x * 1024;
  int s = 0;
#pragma unroll
  for (int k = 0; k < 4; k++) {
    int i = base + k * 256 + threadIdx.x;
    if (i < N) s += counts[i];
  }
  sdata[threadIdx.x] = s;
  __syncthreads();
  for (int off = 128; off > 0; off >>= 1) {
    if (threadIdx.x < off) sdata[threadIdx.x] += sdata[threadIdx.x + off];
    __syncthreads();
  }
  if (threadIdx.x == 0) bsum[blockIdx.x] = sdata[0];
}

__global__ __launch_bounds__(128) void k_scanpart(const int* __restrict__ bsum,
                                                  int* __restrict__ boff, int NB,
                                                  int* __restrict__ row_start, int N) {
  __shared__ int s[129];
  int t = threadIdx.x;
  s[t] = (t < NB) ? bsum[t] : 0;
  __syncthreads();
  if (t == 0) {
    int r = 0;
    for (int b = 0; b < NB; b++) { int v = s[b]; s[b] = r; r += v; }
    row_start[N] = r;  // == E
  }
  __syncthreads();
  if (t < NB) boff[t] = s[t];
}

__global__ __launch_bounds__(256) void k_scanblk(const int* __restrict__ counts,
                                                 const int* __restrict__ boff,
                                                 int* __restrict__ row_start, int N) {
  __shared__ int warp_sums[4];
  int tid = threadIdx.x, lane = tid & 63, wid = tid >> 6;
  int base = blockIdx.x * 1024;
  int i0 = base + tid * 4;
  int c0, c1, c2, c3;
  if (i0 + 3 < N) {
    int4 v = *(const int4*)(counts + i0);
    c0 = v.x; c1 = v.y; c2 = v.z; c3 = v.w;
  } else {
    c0 = (i0 + 0 < N) ? counts[i0 + 0] : 0;
    c1 = (i0 + 1 < N) ? counts[i0 + 1] : 0;
    c2 = (i0 + 2 < N) ? counts[i0 + 2] : 0;
    c3 = (i0 + 3 < N) ? counts[i0 + 3] : 0;
  }
  int s = c0 + c1 + c2 + c3;
  int incl = s;
#pragma unroll
  for (int off = 1; off < 64; off <<= 1) {
    int v = __shfl_up(incl, off);
    if (lane >= off) incl += v;
  }
  if (lane == 63) warp_sums[wid] = incl;
  __syncthreads();
  int pre = 0;
  for (int w = 0; w < wid; w++) pre += warp_sums[w];
  int run = boff[blockIdx.x] + pre + incl - s;
  if (i0 + 0 < N) row_start[i0 + 0] = run; run += c0;
  if (i0 + 1 < N) row_start[i0 + 1] = run; run += c1;
  if (i0 + 2 < N) row_start[i0 + 2] = run; run += c2;
  if (i0 + 3 < N) row_start[i0 + 3] = run;
}

__global__ __launch_bounds__(256) void k_scatter8(const int* __restrict__ row,
                                                  const int* __restrict__ col,
                                                  const int* __restrict__ row_start,
                                                  int* __restrict__ counts,
                                                  int* __restrict__ csr_col, int E, int N) {
  int g = blockIdx.x & 7;
  int bj = blockIdx.x >> 3, nbj = gridDim.x >> 3;
  int lo = (int)(((long long)N * g) >> 3);
  int hi = (int)(((long long)N * (g + 1)) >> 3);
  for (int e = bj * 256 + threadIdx.x; e < E; e += nbj * 256) {
    int r = row[e];
    if (r >= lo && r < hi) {
      int c = col[e];
      int old = atomicSub(&counts[r], 1);  // deg -> 0; fills row backward
      csr_col[row_start[r] + old - 1] = c;
    }
  }
}

// ---- 4 rows/wave, 16 lanes/row: per-edge mask (stored once) + dis ----
__global__ __launch_bounds__(256) void k_mask(const int* __restrict__ rs,
                                              const int* __restrict__ csr_col,
                                              const float* __restrict__ s1,
                                              const float* __restrict__ s2,
                                              float* __restrict__ mask,
                                              float* __restrict__ dis, int N) {
  int lane = threadIdx.x & 63, wid = threadIdx.x >> 6;
  int sub = lane >> 4, sl = lane & 15;
  int r = blockIdx.x * 16 + wid * 4 + sub;
  if (r >= N) return;
  int start = rs[r], end = rs[r + 1];
  float s1r = s1[r];
  float sum = 0.f;
  for (int p = start + sl; p < end; p += 16) {
    float m = maskfn(s1r + s2[csr_col[p]]);
    mask[p] = m;
    sum += m;
  }
#pragma unroll
  for (int off = 1; off < 16; off <<= 1) sum += __shfl_xor(sum, off);
  if (sl == 0) dis[r] = rsqrtf(sum + 1.0f);
}

// ---- One wave per row: out[r] = act( dis[r] * (sum_e mask_e*Hs[col_e] + Hs[r]) ) ----
// LPE = DOUT/8 lanes per edge (uint4 = 8 bf16 feats/lane), EPI = 64/LPE groups,
// 2 edges in flight per group per iteration (latency-bound fix, r8 PMC).
template <int DOUT, bool RELU, bool OUT_BF16>
__global__ __launch_bounds__(256) void k_agg(const int* __restrict__ rs,
                                             const int* __restrict__ csr_col,
                                             const float* __restrict__ mask,
                                             const float* __restrict__ dis,
                                             const uint32_t* __restrict__ Hs,
                                             void* __restrict__ outv, int N) {
  constexpr int LPE = DOUT / 8;
  constexpr int EPI = 64 / LPE;
  constexpr int RW = DOUT / 2;  // row stride in u32
  int lane = threadIdx.x & 63, wid = threadIdx.x >> 6;
  int r = blockIdx.x * 4 + wid;
  if (r >= N) return;
  int start = rs[r], end = rs[r + 1];
  int sub = lane / LPE;
  int fl = lane & (LPE - 1);
  float a0 = 0.f, a1 = 0.f, a2 = 0.f, a3 = 0.f, a4 = 0.f, a5 = 0.f, a6 = 0.f, a7 = 0.f;
  if (sub == 0) {  // self term (mask == 1)
    uint4 u = *(const uint4*)(Hs + (size_t)r * RW + fl * 4);
    a0 = bf_lo(u.x); a1 = bf_hi(u.x); a2 = bf_lo(u.y); a3 = bf_hi(u.y);
    a4 = bf_lo(u.z); a5 = bf_hi(u.z); a6 = bf_lo(u.w); a7 = bf_hi(u.w);
  }
  int p = start;
  for (; p + 2 * EPI <= end; p += 2 * EPI) {
    int eA = p + sub, eB = p + EPI + sub;
    int cA = csr_col[eA], cB = csr_col[eB];
    float mA = mask[eA], mB = mask[eB];
    uint4 uA = *(const uint4*)(Hs + (size_t)cA * RW + fl * 4);
    uint4 uB = *(const uint4*)(Hs + (size_t)cB * RW + fl * 4);
    a0 = fmaf(mA, bf_lo(uA.x), a0); a1 = fmaf(mA, bf_hi(uA.x), a1);
    a2 = fmaf(mA, bf_lo(uA.y), a2); a3 = fmaf(mA, bf_hi(uA.y), a3);
    a4 = fmaf(mA, bf_lo(uA.z), a4); a5 = fmaf(mA, bf_hi(uA.z), a5);
    a6 = fmaf(mA, bf_lo(uA.w), a6); a7 = fmaf(mA, bf_hi(uA.w), a7);
    a0 = fmaf(mB, bf_lo(uB.x), a0); a1 = fmaf(mB, bf_hi(uB.x), a1);
    a2 = fmaf(mB, bf_lo(uB.y), a2); a3 = fmaf(mB, bf_hi(uB.y), a3);
    a4 = fmaf(mB, bf_lo(uB.z), a4); a5 = fmaf(mB, bf_hi(uB.z), a5);
    a6 = fmaf(mB, bf_lo(uB.w), a6); a7 = fmaf(mB, bf_hi(uB.w), a7);
  }
  for (; p < end; p += EPI) {
    int e = p + sub;
    bool v = e < end;
    int c = v ? csr_col[e] : r;
    float m = v ? mask[e] : 0.f;
    uint4 u = *(const uint4*)(Hs + (size_t)c * RW + fl * 4);
    a0 = fmaf(m, bf_lo(u.x), a0); a1 = fmaf(m, bf_hi(u.x), a1);
    a2 = fmaf(m, bf_lo(u.y), a2); a3 = fmaf(m, bf_hi(u.y), a3);
    a4 = fmaf(m, bf_lo(u.z), a4); a5 = fmaf(m, bf_hi(u.z), a5);
    a6 = fmaf(m, bf_lo(u.w), a6); a7 = fmaf(m, bf_hi(u.w), a7);
  }
#pragma unroll
  for (int off = LPE; off < 64; off <<= 1) {
    a0 += __shfl_xor(a0, off); a1 += __shfl_xor(a1, off);
    a2 += __shfl_xor(a2, off); a3 += __shfl_xor(a3, off);
    a4 += __shfl_xor(a4, off); a5 += __shfl_xor(a5, off);
    a6 += __shfl_xor(a6, off); a7 += __shfl_xor(a7, off);
  }
  if (lane < LPE) {
    float dr = dis[r];
    float o[8] = {dr * a0, dr * a1, dr * a2, dr * a3, dr * a4, dr * a5, dr * a6, dr * a7};
    if (RELU) {
#pragma unroll
      for (int q = 0; q < 8; ++q) o[q] = fmaxf(o[q], 0.f);
    }
    if (OUT_BF16) {
      uint4 u;
      u.x = pack_bf2(o[0], o[1]); u.y = pack_bf2(o[2], o[3]);
      u.z = pack_bf2(o[4], o[5]); u.w = pack_bf2(o[6], o[7]);
      *(uint4*)((uint32_t*)outv + (size_t)r * RW + fl * 4) = u;
    } else {
      float* op = (float*)outv + (size_t)r * DOUT + fl * 8;
      *(float4*)op = make_float4(o[0], o[1], o[2], o[3]);
      *(float4*)(op + 4) = make_float4(o[4], o[5], o[6], o[7]);
    }
  }
}

extern "C" void kernel_launch(void* const* d_in, const int* in_sizes, int n_in,
                              void* d_out, int out_size, void* d_ws, size_t ws_size,
                              hipStream_t stream) {
  const float* x      = (const float*)d_in[0];
  const int*   row    = (const int*)d_in[1];
  const int*   col    = (const int*)d_in[2];
  const float* nb_w   = (const float*)d_in[3];
  const float* nb_b   = (const float*)d_in[4];
  const float* self_w = (const float*)d_in[5];
  const float* self_b = (const float*)d_in[6];
  const float* att_w  = (const float*)d_in[7];
  const float* att_b  = (const float*)d_in[8];
  const float* w0     = (const float*)d_in[9];
  const float* w1     = (const float*)d_in[10];
  float* out = (float*)d_out;

  const int N = in_sizes[0] / 128;
  const int E = in_sizes[1];

  char* wp = (char*)d_ws;
  auto alloc = [&](size_t bytes) -> void* {
    void* q = (void*)wp;
    wp += (bytes + 255) & ~(size_t)255;
    return q;
  };
  int*      counts    = (int*)alloc((size_t)N * 4);   // degree, then scatter cursor
  int*      row_start = (int*)alloc((size_t)(N + 1) * 4);
  int*      bsum      = (int*)alloc(512);
  int*      boff      = (int*)alloc(512);
  int*      csr_col   = (int*)alloc((size_t)E * 4);
  float*    mask      = (float*)alloc((size_t)E * 4);
  float*    s1        = (float*)alloc((size_t)N * 4);
  float*    s2        = (float*)alloc((size_t)N * 4);
  float*    dis       = (float*)alloc((size_t)N * 4);
  ushort*   xb        = (ushort*)alloc((size_t)N * 128 * 2);  // layer0 X; reused as x1b
  ushort*   Hs        = (ushort*)alloc((size_t)N * 128 * 2);
  ushort*   w0b       = (ushort*)alloc(16384 * 2);
  ushort*   w1b       = (ushort*)alloc(8192 * 2);
  ushort*   aW0       = (ushort*)alloc(4096 * 2);
  ushort*   aW1       = (ushort*)alloc(4096 * 2);

  const int NB = (N + 1023) / 1024;  // 98 (<=128)
  const int gw = (N + 3) / 4;
  const int gk = (N + 15) / 16;
  const int gm = (N + 63) / 64;
  const int gc = (N * 16 + 255) / 256;

  // ---- CSR build + bf16 conversions ----
  hipMemsetAsync(counts, 0, (size_t)N * 4, stream);
  k_hist8<<<2048, 256, 0, stream>>>(row, counts, E, N);
  k_blocksum<<<NB, 256, 0, stream>>>(counts, bsum, N);
  k_scanpart<<<1, 128, 0, stream>>>(bsum, boff, NB, row_start, N);
  k_scanblk<<<NB, 256, 0, stream>>>(counts, boff, row_start, N);
  k_scatter8<<<2048, 256, 0, stream>>>(row, col, row_start, counts, csr_col, E, N);
  k_cvt<<<gc, 256, 0, stream>>>(x, xb, N * 16);
  k_wpack<<<128, 256, 0, stream>>>(w0, w1, nb_w, self_w, w0b, w1b, aW0, aW1);

  // ---- layer 0: din=128, dout=128, relu; x1b (bf16) aliases xb ----
  k_matt<<<gm, 256, 0, stream>>>(xb, aW0, nb_b, self_b, att_w, att_b, s1, s2, N);
  k_mask<<<gk, 256, 0, stream>>>(row_start, csr_col, s1, s2, mask, dis, N);
  k_mgemm<128><<<gm, 256, 0, stream>>>(xb, w0b, dis, Hs, N);
  k_agg<128, true, true><<<gw, 256, 0, stream>>>(row_start, csr_col, mask, dis,
                                                 (const uint32_t*)Hs, xb, N);

  // ---- layer 1: din=128, dout=64, identity ----
  k_matt<<<gm, 256, 0, stream>>>(xb, aW1, nb_b + 16, self_b + 16, att_w + 32, att_b + 1,
                                 s1, s2, N);
  k_mask<<<gk, 256, 0, stream>>>(row_start, csr_col, s1, s2, mask, dis, N);
  k_mgemm<64><<<gm, 256, 0, stream>>>(xb, w1b, dis, Hs, N);
  k_agg<64, false, false><<<gw, 256, 0, stream>>>(row_start, csr_col, mask, dis,
                                                  (const uint32_t*)Hs, out, N);
}

// Round 10
// 372.822 us; speedup vs baseline: 1.9399x; 1.1961x over previous
//
#include <hip/hip_runtime.h>

// PTDNet-GCN eval forward.
//  - L=2 hard-concrete samples identical in eval -> compute once.
//  - Edge MLP factors into per-node scalars s1/s2; att MLP fused into one MFMA
//    kernel (k_matt). GCN matmuls: bf16 MFMA 16x16x32, B pre-packed.
//  - CSR build: 3-phase bucketed counting sort. r9 PMC showed %8-partitioned
//    hist/scatter bound by cross-XCD line ping-pong on counts/csr lines
//    (WRITE 75MB vs 6.4MB payload, 73us at 5.8% VALU). Now every contended
//    counter/cursor is block-private LDS; global writes are coalesced
//    reservations (A), coalesced slices (B1), or single-CU windows (B2).
//  - k_mask: 4 rows/wave, 16 lanes/row; mask stored once (r7/r8 lessons).
//  - k_agg: DOUT/8 lanes/edge, uint4 gathers, 2 edges in flight (r8 fix).
//  - Hs bf16 pre-scaled by dis[c] in mgemm epilogue.

#define NBKT 64

typedef __attribute__((ext_vector_type(8))) short bf16x8;
typedef __attribute__((ext_vector_type(4))) float f32x4;

__device__ inline float bf_lo(uint32_t u) { return __uint_as_float(u << 16); }
__device__ inline float bf_hi(uint32_t u) { return __uint_as_float(u & 0xffff0000u); }
__device__ inline ushort bf1(float x) {  // RTNE
  uint32_t b = __float_as_uint(x);
  return (ushort)((b + 0x7fffu + ((b >> 16) & 1u)) >> 16);
}
__device__ inline uint32_t pack_bf2(float x, float y) {
  return (uint32_t)bf1(x) | ((uint32_t)bf1(y) << 16);
}
__device__ inline float maskfn(float logit) {
  float g = 1.f / (1.f + __expf(-logit));
  return fminf(fmaxf(fmaf(g, 1.2f, -0.1f), 0.f), 1.f);  // ZETA-GAMMA=1.2, GAMMA=-0.1
}

// ---- Phase A: bin edges into NBKT row-range buckets (block-local 2-pass) ----
__global__ __launch_bounds__(256) void k_binA(const int* __restrict__ row,
                                              const int* __restrict__ col,
                                              int rpp, int E, int PCAP,
                                              uint32_t* __restrict__ part,
                                              int* __restrict__ gcur) {
  __shared__ int cnt[NBKT];
  __shared__ int base[NBKT];
  int tid = threadIdx.x;
  if (tid < NBKT) cnt[tid] = 0;
  __syncthreads();
  int e0 = blockIdx.x * 1024;
  int r[4], c[4], b[4];
  bool v[4];
#pragma unroll
  for (int q = 0; q < 4; ++q) {
    int e = e0 + q * 256 + tid;
    v[q] = e < E;
    if (v[q]) {
      r[q] = __builtin_nontemporal_load(row + e);
      c[q] = __builtin_nontemporal_load(col + e);
      b[q] = r[q] / rpp;
      atomicAdd(&cnt[b[q]], 1);
    }
  }
  __syncthreads();
  if (tid < NBKT) {
    int n = cnt[tid];
    base[tid] = n ? atomicAdd(&gcur[tid], n) : 0;
    cnt[tid] = 0;
  }
  __syncthreads();
#pragma unroll
  for (int q = 0; q < 4; ++q) {
    if (v[q]) {
      int rank = atomicAdd(&cnt[b[q]], 1);
      part[(size_t)b[q] * PCAP + base[b[q]] + rank] =
          ((uint32_t)(r[q] - b[q] * rpp) << 17) | (uint32_t)c[q];
    }
  }
}

// ---- Phase B1: per-bucket LDS histogram -> counts slice (coalesced, no atomics) ----
__global__ __launch_bounds__(1024) void k_bhist(const uint32_t* __restrict__ part,
                                                const int* __restrict__ gcur,
                                                int rpp, int N, int PCAP,
                                                int* __restrict__ counts) {
  __shared__ int h[2048];  // rpp <= 2048
  int tid = threadIdx.x, b = blockIdx.x;
  for (int i = tid; i < rpp; i += 1024) h[i] = 0;
  __syncthreads();
  int n = gcur[b];
  const uint32_t* my = part + (size_t)b * PCAP;
  for (int i = tid; i < n; i += 1024) atomicAdd(&h[my[i] >> 17], 1);
  __syncthreads();
  int r0 = b * rpp;
  for (int i = tid; i < rpp; i += 1024)
    if (r0 + i < N) counts[r0 + i] = h[i];
}

// ---- Phase B2: per-bucket scatter, LDS cursors + row_start slice ----
__global__ __launch_bounds__(1024) void k_bscat(const uint32_t* __restrict__ part,
                                                const int* __restrict__ gcur,
                                                const int* __restrict__ row_start,
                                                int rpp, int N, int PCAP,
                                                int* __restrict__ csr_col) {
  __shared__ int cur[2048];
  __shared__ int rs[2048];
  int tid = threadIdx.x, b = blockIdx.x;
  int r0 = b * rpp;
  for (int i = tid; i < rpp; i += 1024) {
    cur[i] = 0;
    rs[i] = (r0 + i < N) ? row_start[r0 + i] : 0;
  }
  __syncthreads();
  int n = gcur[b];
  const uint32_t* my = part + (size_t)b * PCAP;
  for (int i = tid; i < n; i += 1024) {
    uint32_t u = my[i];
    int rl = u >> 17;
    int pos = rs[rl] + atomicAdd(&cur[rl], 1);
    csr_col[pos] = (int)(u & 0x1FFFFu);
  }
}

// ---- scan kernels (unchanged) ----
__global__ __launch_bounds__(256) void k_blocksum(const int* __restrict__ counts,
                                                  int* __restrict__ bsum, int N) {
  __shared__ int sdata[256];
  int base = blockIdx.x * 1024;
  int s = 0;
#pragma unroll
  for (int k = 0; k < 4; k++) {
    int i = base + k * 256 + threadIdx.x;
    if (i < N) s += counts[i];
  }
  sdata[threadIdx.x] = s;
  __syncthreads();
  for (int off = 128; off > 0; off >>= 1) {
    if (threadIdx.x < off) sdata[threadIdx.x] += sdata[threadIdx.x + off];
    __syncthreads();
  }
  if (threadIdx.x == 0) bsum[blockIdx.x] = sdata[0];
}

__global__ __launch_bounds__(128) void k_scanpart(const int* __restrict__ bsum,
                                                  int* __restrict__ boff, int NB,
                                                  int* __restrict__ row_start, int N) {
  __shared__ int s[129];
  int t = threadIdx.x;
  s[t] = (t < NB) ? bsum[t] : 0;
  __syncthreads();
  if (t == 0) {
    int r = 0;
    for (int b = 0; b < NB; b++) { int v = s[b]; s[b] = r; r += v; }
    row_start[N] = r;  // == E
  }
  __syncthreads();
  if (t < NB) boff[t] = s[t];
}

__global__ __launch_bounds__(256) void k_scanblk(const int* __restrict__ counts,
                                                 const int* __restrict__ boff,
                                                 int* __restrict__ row_start, int N) {
  __shared__ int warp_sums[4];
  int tid = threadIdx.x, lane = tid & 63, wid = tid >> 6;
  int base = blockIdx.x * 1024;
  int i0 = base + tid * 4;
  int c0, c1, c2, c3;
  if (i0 + 3 < N) {
    int4 v = *(const int4*)(counts + i0);
    c0 = v.x; c1 = v.y; c2 = v.z; c3 = v.w;
  } else {
    c0 = (i0 + 0 < N) ? counts[i0 + 0] : 0;
    c1 = (i0 + 1 < N) ? counts[i0 + 1] : 0;
    c2 = (i0 + 2 < N) ? counts[i0 + 2] : 0;
    c3 = (i0 + 3 < N) ? counts[i0 + 3] : 0;
  }
  int s = c0 + c1 + c2 + c3;
  int incl = s;
#pragma unroll
  for (int off = 1; off < 64; off <<= 1) {
    int v = __shfl_up(incl, off);
    if (lane >= off) incl += v;
  }
  if (lane == 63) warp_sums[wid] = incl;
  __syncthreads();
  int pre = 0;
  for (int w = 0; w < wid; w++) pre += warp_sums[w];
  int run = boff[blockIdx.x] + pre + incl - s;
  if (i0 + 0 < N) row_start[i0 + 0] = run; run += c0;
  if (i0 + 1 < N) row_start[i0 + 1] = run; run += c1;
  if (i0 + 2 < N) row_start[i0 + 2] = run; run += c2;
  if (i0 + 3 < N) row_start[i0 + 3] = run;
}

// ---- f32 -> bf16 row conversion (8 elems/thread) ----
__global__ __launch_bounds__(256) void k_cvt(const float* __restrict__ X,
                                             ushort* __restrict__ Xb, int n8) {
  int i = blockIdx.x * 256 + threadIdx.x;
  if (i >= n8) return;
  const float4* s = (const float4*)(X + (size_t)i * 8);
  float4 v0 = s[0], v1 = s[1];
  uint4 o;
  o.x = pack_bf2(v0.x, v0.y); o.y = pack_bf2(v0.z, v0.w);
  o.z = pack_bf2(v1.x, v1.y); o.w = pack_bf2(v1.z, v1.w);
  *(uint4*)(Xb + (size_t)i * 8) = o;
}

// ---- pack all weight matrices into MFMA B-fragment order ----
__global__ __launch_bounds__(256) void k_wpack(const float* __restrict__ w0,
                                               const float* __restrict__ w1,
                                               const float* __restrict__ nbw,
                                               const float* __restrict__ sfw,
                                               ushort* __restrict__ w0b,
                                               ushort* __restrict__ w1b,
                                               ushort* __restrict__ aW0,
                                               ushort* __restrict__ aW1) {
  int t = blockIdx.x * 256 + threadIdx.x;
  if (t < 16384) {
    int j = t & 7, l = (t >> 3) & 63, g = (t >> 9) & 3, ct = t >> 11;
    int k = g * 32 + (l >> 4) * 8 + j;
    w0b[t] = bf1(w0[k * 128 + ct * 16 + (l & 15)]);
  } else if (t < 24576) {
    int rem = t - 16384;
    int j = rem & 7, l = (rem >> 3) & 63, g = (rem >> 9) & 3, ct = rem >> 11;
    int k = g * 32 + (l >> 4) * 8 + j;
    w1b[rem] = bf1(w1[k * 64 + ct * 16 + (l & 15)]);
  } else if (t < 32768) {
    int rem = t - 24576;            // [0, 8192)
    int layer = rem >> 12;          // 4096 per layer
    int full = rem & 4095;          // ct(1b) | g(2b) | l(6b) | j(3b)
    int j = full & 7, l = (full >> 3) & 63, g = (full >> 9) & 3, ct = full >> 11;
    int k = g * 32 + (l >> 4) * 8 + j;
    const float* src = (ct == 0 ? nbw : sfw) + layer * 2048;  // [128][16] slab
    ushort* dst = (layer == 0 ? aW0 : aW1);
    dst[full] = bf1(src[k * 16 + (l & 15)]);
  }
}

// ---- fused attention MLP: s1/s2 = rowwise relu(Xb@W+b) . aw  (MFMA + shfl) ----
__global__ __launch_bounds__(256) void k_matt(const ushort* __restrict__ Xb,
                                              const ushort* __restrict__ Wp,
                                              const float* __restrict__ b1,
                                              const float* __restrict__ b2,
                                              const float* __restrict__ aw,
                                              const float* __restrict__ attb,
                                              float* __restrict__ s1,
                                              float* __restrict__ s2, int N) {
  int tid = threadIdx.x, w = tid >> 6, l = tid & 63;
  int n0 = blockIdx.x * 64 + w * 16;
  int arow = n0 + (l & 15);
  if (arow >= N) arow = N - 1;
  const ushort* xr = Xb + (size_t)arow * 128 + (l >> 4) * 8;
  bf16x8 a[4];
#pragma unroll
  for (int g = 0; g < 4; ++g) a[g] = *(const bf16x8*)(xr + g * 32);
  f32x4 acc0 = {0.f, 0.f, 0.f, 0.f}, acc1 = acc0;
  const ushort* wp = Wp + l * 8;
#pragma unroll
  for (int g = 0; g < 4; ++g) {
    bf16x8 b0 = *(const bf16x8*)(wp + (size_t)g * 512);
    bf16x8 b1f = *(const bf16x8*)(wp + (size_t)(4 + g) * 512);
    acc0 = __builtin_amdgcn_mfma_f32_16x16x32_bf16(a[g], b0, acc0, 0, 0, 0);
    acc1 = __builtin_amdgcn_mfma_f32_16x16x32_bf16(a[g], b1f, acc1, 0, 0, 0);
  }
  int coln = l & 15;
  float awn = aw[coln], aws = aw[16 + coln];
  float bb1 = b1[coln], bb2 = b2[coln];
  float v1[4], v2[4];
#pragma unroll
  for (int r = 0; r < 4; ++r) {
    v1[r] = fmaxf(acc0[r] + bb1, 0.f) * awn;
    v2[r] = fmaxf(acc1[r] + bb2, 0.f) * aws;
  }
#pragma unroll
  for (int off = 1; off < 16; off <<= 1) {
#pragma unroll
    for (int r = 0; r < 4; ++r) {
      v1[r] += __shfl_xor(v1[r], off);
      v2[r] += __shfl_xor(v2[r], off);
    }
  }
  if (coln == 0) {
    int r0 = n0 + (l >> 4) * 4;  // C/D: col=lane&15, row=(lane>>4)*4+reg [m89]
    float ab = attb[0];
#pragma unroll
    for (int r = 0; r < 4; ++r) {
      int row = r0 + r;
      if (row < N) { s1[row] = v1[r]; s2[row] = v2[r] + ab; }
    }
  }
}

// ---- MFMA GEMM: H[N,DOUT](bf16) = dis[n] * (Xb[N,128] @ Wp)[n,:] ----
template <int DOUT>
__global__ __launch_bounds__(256) void k_mgemm(const ushort* __restrict__ Xb,
                                               const ushort* __restrict__ Wp,
                                               const float* __restrict__ dis,
                                               ushort* __restrict__ H, int N) {
  constexpr int NCT = DOUT / 16;
  int tid = threadIdx.x, w = tid >> 6, l = tid & 63;
  int n0 = blockIdx.x * 64 + w * 16;
  int arow = n0 + (l & 15);
  if (arow >= N) arow = N - 1;
  const ushort* xr = Xb + (size_t)arow * 128 + (l >> 4) * 8;
  bf16x8 a[4];
#pragma unroll
  for (int g = 0; g < 4; ++g) a[g] = *(const bf16x8*)(xr + g * 32);
  f32x4 acc[NCT];
#pragma unroll
  for (int ct = 0; ct < NCT; ++ct) acc[ct] = (f32x4){0.f, 0.f, 0.f, 0.f};
  const ushort* wp = Wp + l * 8;
#pragma unroll
  for (int ct = 0; ct < NCT; ++ct) {
#pragma unroll
    for (int g = 0; g < 4; ++g) {
      bf16x8 b = *(const bf16x8*)(wp + (size_t)(ct * 4 + g) * 512);
      acc[ct] = __builtin_amdgcn_mfma_f32_16x16x32_bf16(a[g], b, acc[ct], 0, 0, 0);
    }
  }
  int r0 = n0 + (l >> 4) * 4;  // C/D: col=lane&15, row=(lane>>4)*4+reg [m89]
  float scale[4];
#pragma unroll
  for (int r = 0; r < 4; ++r) scale[r] = (r0 + r < N) ? dis[r0 + r] : 0.f;
  int coln = l & 15;
#pragma unroll
  for (int ct = 0; ct < NCT; ++ct) {
    int col = ct * 16 + coln;
#pragma unroll
    for (int r = 0; r < 4; ++r) {
      int row = r0 + r;
      if (row < N) H[(size_t)row * DOUT + col] = bf1(acc[ct][r] * scale[r]);
    }
  }
}

// ---- 4 rows/wave, 16 lanes/row: per-edge mask (stored once) + dis ----
__global__ __launch_bounds__(256) void k_mask(const int* __restrict__ rs,
                                              const int* __restrict__ csr_col,
                                              const float* __restrict__ s1,
                                              const float* __restrict__ s2,
                                              float* __restrict__ mask,
                                              float* __restrict__ dis, int N) {
  int lane = threadIdx.x & 63, wid = threadIdx.x >> 6;
  int sub = lane >> 4, sl = lane & 15;
  int r = blockIdx.x * 16 + wid * 4 + sub;
  if (r >= N) return;
  int start = rs[r], end = rs[r + 1];
  float s1r = s1[r];
  float sum = 0.f;
  for (int p = start + sl; p < end; p += 16) {
    float m = maskfn(s1r + s2[csr_col[p]]);
    mask[p] = m;
    sum += m;
  }
#pragma unroll
  for (int off = 1; off < 16; off <<= 1) sum += __shfl_xor(sum, off);
  if (sl == 0) dis[r] = rsqrtf(sum + 1.0f);
}

// ---- One wave per row: out[r] = act( dis[r] * (sum_e mask_e*Hs[col_e] + Hs[r]) ) ----
template <int DOUT, bool RELU, bool OUT_BF16>
__global__ __launch_bounds__(256) void k_agg(const int* __restrict__ rs,
                                             const int* __restrict__ csr_col,
                                             const float* __restrict__ mask,
                                             const float* __restrict__ dis,
                                             const uint32_t* __restrict__ Hs,
                                             void* __restrict__ outv, int N) {
  constexpr int LPE = DOUT / 8;
  constexpr int EPI = 64 / LPE;
  constexpr int RW = DOUT / 2;  // row stride in u32
  int lane = threadIdx.x & 63, wid = threadIdx.x >> 6;
  int r = blockIdx.x * 4 + wid;
  if (r >= N) return;
  int start = rs[r], end = rs[r + 1];
  int sub = lane / LPE;
  int fl = lane & (LPE - 1);
  float a0 = 0.f, a1 = 0.f, a2 = 0.f, a3 = 0.f, a4 = 0.f, a5 = 0.f, a6 = 0.f, a7 = 0.f;
  if (sub == 0) {  // self term (mask == 1)
    uint4 u = *(const uint4*)(Hs + (size_t)r * RW + fl * 4);
    a0 = bf_lo(u.x); a1 = bf_hi(u.x); a2 = bf_lo(u.y); a3 = bf_hi(u.y);
    a4 = bf_lo(u.z); a5 = bf_hi(u.z); a6 = bf_lo(u.w); a7 = bf_hi(u.w);
  }
  int p = start;
  for (; p + 2 * EPI <= end; p += 2 * EPI) {
    int eA = p + sub, eB = p + EPI + sub;
    int cA = csr_col[eA], cB = csr_col[eB];
    float mA = mask[eA], mB = mask[eB];
    uint4 uA = *(const uint4*)(Hs + (size_t)cA * RW + fl * 4);
    uint4 uB = *(const uint4*)(Hs + (size_t)cB * RW + fl * 4);
    a0 = fmaf(mA, bf_lo(uA.x), a0); a1 = fmaf(mA, bf_hi(uA.x), a1);
    a2 = fmaf(mA, bf_lo(uA.y), a2); a3 = fmaf(mA, bf_hi(uA.y), a3);
    a4 = fmaf(mA, bf_lo(uA.z), a4); a5 = fmaf(mA, bf_hi(uA.z), a5);
    a6 = fmaf(mA, bf_lo(uA.w), a6); a7 = fmaf(mA, bf_hi(uA.w), a7);
    a0 = fmaf(mB, bf_lo(uB.x), a0); a1 = fmaf(mB, bf_hi(uB.x), a1);
    a2 = fmaf(mB, bf_lo(uB.y), a2); a3 = fmaf(mB, bf_hi(uB.y), a3);
    a4 = fmaf(mB, bf_lo(uB.z), a4); a5 = fmaf(mB, bf_hi(uB.z), a5);
    a6 = fmaf(mB, bf_lo(uB.w), a6); a7 = fmaf(mB, bf_hi(uB.w), a7);
  }
  for (; p < end; p += EPI) {
    int e = p + sub;
    bool v = e < end;
    int c = v ? csr_col[e] : r;
    float m = v ? mask[e] : 0.f;
    uint4 u = *(const uint4*)(Hs + (size_t)c * RW + fl * 4);
    a0 = fmaf(m, bf_lo(u.x), a0); a1 = fmaf(m, bf_hi(u.x), a1);
    a2 = fmaf(m, bf_lo(u.y), a2); a3 = fmaf(m, bf_hi(u.y), a3);
    a4 = fmaf(m, bf_lo(u.z), a4); a5 = fmaf(m, bf_hi(u.z), a5);
    a6 = fmaf(m, bf_lo(u.w), a6); a7 = fmaf(m, bf_hi(u.w), a7);
  }
#pragma unroll
  for (int off = LPE; off < 64; off <<= 1) {
    a0 += __shfl_xor(a0, off); a1 += __shfl_xor(a1, off);
    a2 += __shfl_xor(a2, off); a3 += __shfl_xor(a3, off);
    a4 += __shfl_xor(a4, off); a5 += __shfl_xor(a5, off);
    a6 += __shfl_xor(a6, off); a7 += __shfl_xor(a7, off);
  }
  if (lane < LPE) {
    float dr = dis[r];
    float o[8] = {dr * a0, dr * a1, dr * a2, dr * a3, dr * a4, dr * a5, dr * a6, dr * a7};
    if (RELU) {
#pragma unroll
      for (int q = 0; q < 8; ++q) o[q] = fmaxf(o[q], 0.f);
    }
    if (OUT_BF16) {
      uint4 u;
      u.x = pack_bf2(o[0], o[1]); u.y = pack_bf2(o[2], o[3]);
      u.z = pack_bf2(o[4], o[5]); u.w = pack_bf2(o[6], o[7]);
      *(uint4*)((uint32_t*)outv + (size_t)r * RW + fl * 4) = u;
    } else {
      float* op = (float*)outv + (size_t)r * DOUT + fl * 8;
      *(float4*)op = make_float4(o[0], o[1], o[2], o[3]);
      *(float4*)(op + 4) = make_float4(o[4], o[5], o[6], o[7]);
    }
  }
}

extern "C" void kernel_launch(void* const* d_in, const int* in_sizes, int n_in,
                              void* d_out, int out_size, void* d_ws, size_t ws_size,
                              hipStream_t stream) {
  const float* x      = (const float*)d_in[0];
  const int*   row    = (const int*)d_in[1];
  const int*   col    = (const int*)d_in[2];
  const float* nb_w   = (const float*)d_in[3];
  const float* nb_b   = (const float*)d_in[4];
  const float* self_w = (const float*)d_in[5];
  const float* self_b = (const float*)d_in[6];
  const float* att_w  = (const float*)d_in[7];
  const float* att_b  = (const float*)d_in[8];
  const float* w0     = (const float*)d_in[9];
  const float* w1     = (const float*)d_in[10];
  float* out = (float*)d_out;

  const int N = in_sizes[0] / 128;
  const int E = in_sizes[1];
  const int rpp = (N + NBKT - 1) / NBKT;             // 1563 (<= 2048 LDS limit)
  const int PCAP = (((E / NBKT) + 4096 + 255) / 256) * 256;  // mean + ~26 sigma

  char* wp = (char*)d_ws;
  auto alloc = [&](size_t bytes) -> void* {
    void* q = (void*)wp;
    wp += (bytes + 255) & ~(size_t)255;
    return q;
  };
  int*      counts    = (int*)alloc((size_t)N * 4);
  int*      row_start = (int*)alloc((size_t)(N + 1) * 4);
  int*      bsum      = (int*)alloc(512);
  int*      boff      = (int*)alloc(512);
  int*      gcur      = (int*)alloc(NBKT * 4);
  int*      csr_col   = (int*)alloc((size_t)E * 4);
  float*    mask      = (float*)alloc((size_t)E * 4);
  float*    s1        = (float*)alloc((size_t)N * 4);
  float*    s2        = (float*)alloc((size_t)N * 4);
  float*    dis       = (float*)alloc((size_t)N * 4);
  ushort*   xb        = (ushort*)alloc((size_t)N * 128 * 2);  // layer0 X; reused as x1b
  ushort*   Hs        = (ushort*)alloc((size_t)N * 128 * 2);  // also phase-A/B bucket
  ushort*   w0b       = (ushort*)alloc(16384 * 2);            // buffer (dead by mgemm)
  ushort*   w1b       = (ushort*)alloc(8192 * 2);
  ushort*   aW0       = (ushort*)alloc(4096 * 2);
  ushort*   aW1       = (ushort*)alloc(4096 * 2);
  uint32_t* part      = (uint32_t*)Hs;  // NBKT*PCAP*4 = ~7.5MB < 25.6MB

  const int NB = (N + 1023) / 1024;  // 98 (<=128)
  const int gw = (N + 3) / 4;
  const int gk = (N + 15) / 16;
  const int gm = (N + 63) / 64;
  const int gc = (N * 16 + 255) / 256;
  const int gA = (E + 1023) / 1024;

  // ---- CSR build: bin -> bucket-hist -> scan -> bucket-scatter ----
  hipMemsetAsync(gcur, 0, NBKT * 4, stream);
  k_binA<<<gA, 256, 0, stream>>>(row, col, rpp, E, PCAP, part, gcur);
  k_bhist<<<NBKT, 1024, 0, stream>>>(part, gcur, rpp, N, PCAP, counts);
  k_blocksum<<<NB, 256, 0, stream>>>(counts, bsum, N);
  k_scanpart<<<1, 128, 0, stream>>>(bsum, boff, NB, row_start, N);
  k_scanblk<<<NB, 256, 0, stream>>>(counts, boff, row_start, N);
  k_bscat<<<NBKT, 1024, 0, stream>>>(part, gcur, row_start, rpp, N, PCAP, csr_col);
  k_cvt<<<gc, 256, 0, stream>>>(x, xb, N * 16);
  k_wpack<<<128, 256, 0, stream>>>(w0, w1, nb_w, self_w, w0b, w1b, aW0, aW1);

  // ---- layer 0: din=128, dout=128, relu; x1b (bf16) aliases xb ----
  k_matt<<<gm, 256, 0, stream>>>(xb, aW0, nb_b, self_b, att_w, att_b, s1, s2, N);
  k_mask<<<gk, 256, 0, stream>>>(row_start, csr_col, s1, s2, mask, dis, N);
  k_mgemm<128><<<gm, 256, 0, stream>>>(xb, w0b, dis, Hs, N);
  k_agg<128, true, true><<<gw, 256, 0, stream>>>(row_start, csr_col, mask, dis,
                                                 (const uint32_t*)Hs, xb, N);

  // ---- layer 1: din=128, dout=64, identity ----
  k_matt<<<gm, 256, 0, stream>>>(xb, aW1, nb_b + 16, self_b + 16, att_w + 32, att_b + 1,
                                 s1, s2, N);
  k_mask<<<gk, 256, 0, stream>>>(row_start, csr_col, s1, s2, mask, dis, N);
  k_mgemm<64><<<gm, 256, 0, stream>>>(xb, w1b, dis, Hs, N);
  k_agg<64, false, false><<<gw, 256, 0, stream>>>(row_start, csr_col, mask, dis,
                                                  (const uint32_t*)Hs, out, N);
}